// Round 1
// baseline (5150.079 us; speedup 1.0000x reference)
//
#include <hip/hip_runtime.h>
#include <math.h>

static constexpr int BSZ  = 256;
static constexpr int NF   = 66;
static constexpr int DM   = 512;
static constexpr int DCTN = 10;
static constexpr int VL   = 20;   // KS + output_n
static constexpr int NWIN = 31;   // vn

// ---------------- workspace layout (floats) ----------------
static constexpr size_t OFF_DCT    = 0;                                   // 400 (pad 512)
static constexpr size_t OFF_WP     = 512;                                 // 18*512*512
static constexpr size_t OFF_DCTATT = OFF_WP + 18ull*DM*DM;                // 256*66*10
static constexpr size_t OFF_DCTIN  = OFF_DCTATT + (size_t)BSZ*NF*DCTN;    // 256*66*10
static constexpr size_t OFF_ATT    = OFF_DCTIN + (size_t)BSZ*NF*DCTN;     // 256*32 (padded)
static constexpr size_t OFF_QT     = OFF_ATT + (size_t)BSZ*32;            // 256*512
static constexpr size_t OFF_S      = OFF_QT + (size_t)BSZ*DM;
// conv-phase aliases over scratch region
static constexpr size_t OFF_T1K  = OFF_S;                                 // 256*35*512
static constexpr size_t OFF_KEYT = OFF_T1K + (size_t)BSZ*35*DM;           // 256*31*512
static constexpr size_t OFF_T1Q  = OFF_KEYT + (size_t)BSZ*31*DM;          // 256*5*512
// gcn-phase aliases over the same scratch region (conv results dead by then)
static constexpr size_t OFF_H0 = OFF_S;
static constexpr size_t OFF_HA = OFF_H0 + (size_t)BSZ*NF*DM;
static constexpr size_t OFF_HB = OFF_HA + (size_t)BSZ*NF*DM;

// ---------------- constant builders ----------------
__global__ void k_build_dct(float* __restrict__ dct) {
    int idx = threadIdx.x;
    if (idx < 400) {
        int k = idx / 20, i = idx % 20;
        double w = (k == 0) ? 0.22360679774997896 : 0.31622776601683794; // sqrt(1/20), sqrt(2/20)
        dct[idx] = (float)(w * cos(3.14159265358979323846 * (i + 0.5) * k / 20.0));
    }
}

// Wp = beta*W + (1-beta)*I, per (stage,layer) matrix
__global__ __launch_bounds__(256) void k_build_wp(const float* __restrict__ Wl,
                                                  float* __restrict__ Wp) {
    size_t idx = (size_t)blockIdx.x * 256 + threadIdx.x;  // 18*512*512 total
    int l = (int)((idx >> 18) % 6);
    float beta = logf(0.5f / (float)(l + 1) + 1.0f);
    int r = (int)((idx >> 9) & 511), c = (int)(idx & 511);
    Wp[idx] = beta * Wl[idx] + ((r == c) ? (1.0f - beta) : 0.0f);
}

// ---------------- conv stack ----------------
// out[b][t][o] = relu(sum_{i<66,k<6} src[b][T0+t+k][i]/1000 * w[o][i][k])
template<int T, int T0>
__global__ __launch_bounds__(512) void k_conv1(const float* __restrict__ src,
                                               const float* __restrict__ w,
                                               float* __restrict__ out) {
    __shared__ float s_src[50 * NF];
    int b = blockIdx.x;
    const float* sb = src + (size_t)b * 50 * NF;
    for (int i = threadIdx.x; i < 50 * NF; i += 512) s_src[i] = sb[i] * 1e-3f;
    __syncthreads();
    int o = threadIdx.x;
    float acc[T];
#pragma unroll
    for (int t = 0; t < T; ++t) acc[t] = 0.f;
    const float* wo = w + (size_t)o * (NF * 6);
    for (int i = 0; i < NF; ++i) {
#pragma unroll
        for (int k = 0; k < 6; ++k) {
            float wv = wo[i * 6 + k];
#pragma unroll
            for (int t = 0; t < T; ++t)
                acc[t] += s_src[(T0 + t + k) * NF + i] * wv;
        }
    }
    for (int t = 0; t < T; ++t)
        out[((size_t)b * T + t) * DM + o] = fmaxf(acc[t], 0.f);
}

// out[b][t][o] = relu(sum_{i<512,k<5} in[b][t+k][i] * w[o][i][k])
template<int TIN>
__global__ __launch_bounds__(512) void k_conv2(const float* __restrict__ in,
                                               const float* __restrict__ w,
                                               float* __restrict__ out) {
    constexpr int TOUT = TIN - 4;
    __shared__ float s_in[TIN * 256];
    int b = blockIdx.x, o = threadIdx.x;
    float acc[TOUT];
#pragma unroll
    for (int t = 0; t < TOUT; ++t) acc[t] = 0.f;
    for (int c0 = 0; c0 < DM; c0 += 256) {
        __syncthreads();
        for (int idx = threadIdx.x; idx < TIN * 256; idx += 512) {
            int t = idx >> 8, c = idx & 255;
            s_in[idx] = in[((size_t)b * TIN + t) * DM + c0 + c];
        }
        __syncthreads();
        for (int ci = 0; ci < 256; ++ci) {
            float xv[TIN];
#pragma unroll
            for (int t = 0; t < TIN; ++t) xv[t] = s_in[t * 256 + ci];
            const float* wp = w + ((size_t)o * DM + c0 + ci) * 5;
#pragma unroll
            for (int k = 0; k < 5; ++k) {
                float wv = wp[k];
#pragma unroll
                for (int t = 0; t < TOUT; ++t) acc[t] += xv[t + k] * wv;
            }
        }
    }
    for (int t = 0; t < TOUT; ++t)
        out[((size_t)b * TOUT + t) * DM + o] = fmaxf(acc[t], 0.f);
}

// score -> normalized att (one block per batch)
__global__ __launch_bounds__(512) void k_att(const float* __restrict__ qt,
                                             const float* __restrict__ keyt,
                                             float* __restrict__ att) {
    int b = blockIdx.x;
    __shared__ float s_sc[NWIN];
    int wave = threadIdx.x >> 6, lane = threadIdx.x & 63;
    const float* qp = qt + (size_t)b * DM;
    for (int k = wave; k < NWIN; k += 8) {
        const float* kp = keyt + ((size_t)b * NWIN + k) * DM;
        float p = 0.f;
        for (int d = lane; d < DM; d += 64) p += qp[d] * kp[d];
#pragma unroll
        for (int off = 32; off; off >>= 1) p += __shfl_down(p, off);
        if (lane == 0) s_sc[k] = p + 1e-15f;
    }
    __syncthreads();
    if (threadIdx.x == 0) {
        float s = 0.f;
        for (int k = 0; k < NWIN; ++k) s += s_sc[k];
        float inv = 1.f / s;
        for (int k = 0; k < NWIN; ++k) att[(size_t)b * 32 + k] = s_sc[k] * inv;
    }
}

// dct_att[b][f][d] = sum_l dct[d][l] * (sum_v att[v]*src[b][v+l][f])
// dct_in [b][f][d] = sum_l dct[d][l] * src[b][idx2[l]][f]
__global__ __launch_bounds__(256) void k_dctatt(const float* __restrict__ src,
                                                const float* __restrict__ att,
                                                const float* __restrict__ dct,
                                                float* __restrict__ dct_att,
                                                float* __restrict__ dct_in) {
    int b = blockIdx.x;
    __shared__ float s_src[50 * NF];
    __shared__ float s_att[NWIN];
    __shared__ float s_ws[VL * NF];
    const float* sb = src + (size_t)b * 50 * NF;
    for (int i = threadIdx.x; i < 50 * NF; i += 256) s_src[i] = sb[i];
    if (threadIdx.x < NWIN) s_att[threadIdx.x] = att[(size_t)b * 32 + threadIdx.x];
    __syncthreads();
    for (int i = threadIdx.x; i < VL * NF; i += 256) {
        int l = i / NF, f = i % NF;
        float a = 0.f;
        for (int v = 0; v < NWIN; ++v) a += s_att[v] * s_src[(v + l) * NF + f];
        s_ws[i] = a;
    }
    __syncthreads();
    for (int i = threadIdx.x; i < NF * DCTN; i += 256) {
        int f = i / DCTN, d = i % DCTN;
        float a = 0.f, c = 0.f;
#pragma unroll
        for (int l = 0; l < VL; ++l) {
            float dm = dct[d * VL + l];
            a += dm * s_ws[l * NF + f];
            int t2 = (l < 10) ? (40 + l) : 49;
            c += dm * s_src[t2 * NF + f];
        }
        dct_att[(size_t)b * NF * DCTN + i] = a;
        dct_in[(size_t)b * NF * DCTN + i] = c;
    }
}

// h0 = tanh(x @ Win) (+ his); x = [dct_in | dct_att] per (b,f)
__global__ __launch_bounds__(512) void k_h0(const float* __restrict__ dct_in,
                                            const float* __restrict__ dct_att,
                                            const float* __restrict__ Win,
                                            const float* __restrict__ his,
                                            float* __restrict__ h0) {
    int b = blockIdx.x, d = threadIdx.x;
    __shared__ float s_x[NF * VL];
    for (int i = threadIdx.x; i < NF * DCTN; i += 512) {
        int f = i / DCTN, c = i % DCTN;
        s_x[f * VL + c]      = dct_in[(size_t)b * NF * DCTN + i];
        s_x[f * VL + 10 + c] = dct_att[(size_t)b * NF * DCTN + i];
    }
    __syncthreads();
    float w[VL];
#pragma unroll
    for (int c = 0; c < VL; ++c) w[c] = Win[c * DM + d];
    const float* hisb = his + (size_t)b * NF * DM + d;
    float* h0b = h0 + (size_t)b * NF * DM + d;
    for (int f = 0; f < NF; ++f) {
        float a = 0.f;
#pragma unroll
        for (int c = 0; c < VL; ++c) a += s_x[f * VL + c] * w[c];
        float v = tanhf(a);
        if (his) v += hisb[(size_t)f * DM];
        h0b[(size_t)f * DM] = v;
    }
}

// m[b][n][d] = 0.9 * sum_mm A[n][mm]*h[b][mm][d] + 0.1*h0[b][n][d]
__global__ __launch_bounds__(512) void k_amix(const float* __restrict__ A,
                                              const float* __restrict__ h,
                                              const float* __restrict__ h0,
                                              float* __restrict__ m) {
    int b = blockIdx.x, d = threadIdx.x;
    float hreg[NF];
    const float* hb = h + (size_t)b * NF * DM + d;
#pragma unroll
    for (int mm = 0; mm < NF; ++mm) hreg[mm] = hb[(size_t)mm * DM];
    const float* h0b = h0 + (size_t)b * NF * DM + d;
    float* mb = m + (size_t)b * NF * DM + d;
    for (int n = 0; n < NF; ++n) {
        float a = 0.f;
        const float* An = A + n * NF;
#pragma unroll
        for (int mm = 0; mm < NF; ++mm) a += An[mm] * hreg[mm];
        mb[(size_t)n * DM] = 0.9f * a + 0.1f * h0b[(size_t)n * DM];
    }
}

// C = tanh(A @ B); A: [16896][512], B: [512][512], 64x64 tile, 4x4 micro
__global__ __launch_bounds__(256) void k_gemm_tanh(const float* __restrict__ A,
                                                   const float* __restrict__ B,
                                                   float* __restrict__ C) {
    __shared__ float sA[32][68];
    __shared__ float sB[32][68];
    int tid = threadIdx.x;
    int row0 = blockIdx.x * 64, col0 = blockIdx.y * 64;
    int tm = (tid & 15) * 4, tn = (tid >> 4) * 4;
    float acc[4][4] = {};
    for (int k0 = 0; k0 < DM; k0 += 32) {
#pragma unroll
        for (int ld = 0; ld < 2; ++ld) {
            int idx = tid + ld * 256;
            int r = idx >> 3, c4 = (idx & 7) * 4;
            const float4 va = *(const float4*)(A + (size_t)(row0 + r) * DM + k0 + c4);
            sA[c4 + 0][r] = va.x; sA[c4 + 1][r] = va.y;
            sA[c4 + 2][r] = va.z; sA[c4 + 3][r] = va.w;
            int r2 = idx >> 4, c2 = (idx & 15) * 4;
            const float4 vb = *(const float4*)(B + (size_t)(k0 + r2) * DM + col0 + c2);
            *(float4*)&sB[r2][c2] = vb;
        }
        __syncthreads();
#pragma unroll
        for (int k = 0; k < 32; ++k) {
            float4 a = *(const float4*)&sA[k][tm];
            float4 b = *(const float4*)&sB[k][tn];
            acc[0][0] += a.x * b.x; acc[0][1] += a.x * b.y; acc[0][2] += a.x * b.z; acc[0][3] += a.x * b.w;
            acc[1][0] += a.y * b.x; acc[1][1] += a.y * b.y; acc[1][2] += a.y * b.z; acc[1][3] += a.y * b.w;
            acc[2][0] += a.z * b.x; acc[2][1] += a.z * b.y; acc[2][2] += a.z * b.z; acc[2][3] += a.z * b.w;
            acc[3][0] += a.w * b.x; acc[3][1] += a.w * b.y; acc[3][2] += a.w * b.z; acc[3][3] += a.w * b.w;
        }
        __syncthreads();
    }
#pragma unroll
    for (int i = 0; i < 4; ++i) {
        float4 o;
        o.x = tanhf(acc[i][0]); o.y = tanhf(acc[i][1]);
        o.z = tanhf(acc[i][2]); o.w = tanhf(acc[i][3]);
        *(float4*)(C + (size_t)(row0 + tm + i) * DM + col0 + tn) = o;
    }
}

// dct_out = dct_in + (h @ Wout)[:, :, :10];  out_gcn[b][l][f] = sum_d dct[d][l]*dct_out[b][f][d]
__global__ __launch_bounds__(256) void k_out(const float* __restrict__ h,
                                             const float* __restrict__ Wout,
                                             const float* __restrict__ dct,
                                             float* __restrict__ dct_in,
                                             float* __restrict__ outj) {
    int b = blockIdx.x;
    __shared__ float s_do[NF * DCTN];
    int wave = threadIdx.x >> 6, lane = threadIdx.x & 63;
    const float* hb = h + (size_t)b * NF * DM;
    for (int i = wave; i < NF * DCTN; i += 4) {
        int f = i / DCTN, c = i % DCTN;
        float p = 0.f;
        for (int d = lane; d < DM; d += 64) p += hb[(size_t)f * DM + d] * Wout[d * VL + c];
#pragma unroll
        for (int off = 32; off; off >>= 1) p += __shfl_down(p, off);
        if (lane == 0) s_do[i] = p + dct_in[(size_t)b * NF * DCTN + i];
    }
    __syncthreads();
    for (int i = threadIdx.x; i < NF * DCTN; i += 256)
        dct_in[(size_t)b * NF * DCTN + i] = s_do[i];
    for (int i = threadIdx.x; i < VL * NF; i += 256) {
        int l = i / NF, f = i % NF;
        float a = 0.f;
#pragma unroll
        for (int d = 0; d < DCTN; ++d) a += dct[d * VL + l] * s_do[f * DCTN + d];
        outj[((size_t)b * VL + l) * NF + f] = a;
    }
}

extern "C" void kernel_launch(void* const* d_in, const int* in_sizes, int n_in,
                              void* d_out, int out_size, void* d_ws, size_t ws_size,
                              hipStream_t stream) {
    const float* src  = (const float*)d_in[0];
    const float* wQ1  = (const float*)d_in[1];
    const float* wQ2  = (const float*)d_in[2];
    const float* wK1  = (const float*)d_in[3];
    const float* wK2  = (const float*)d_in[4];
    const float* Win  = (const float*)d_in[5];
    const float* Agcn = (const float*)d_in[6];
    const float* Wl   = (const float*)d_in[7];
    const float* Wout = (const float*)d_in[8];
    float* ws  = (float*)d_ws;
    float* out = (float*)d_out;

    float* dct     = ws + OFF_DCT;
    float* Wp      = ws + OFF_WP;
    float* dct_att = ws + OFF_DCTATT;
    float* dct_in  = ws + OFF_DCTIN;
    float* att     = ws + OFF_ATT;
    float* qt      = ws + OFF_QT;
    float* t1K     = ws + OFF_T1K;
    float* keyt    = ws + OFF_KEYT;
    float* t1Q     = ws + OFF_T1Q;
    float* h0      = ws + OFF_H0;
    float* hA      = ws + OFF_HA;
    float* hB      = ws + OFF_HB;

    k_build_dct<<<1, 512, 0, stream>>>(dct);
    k_build_wp<<<18432, 256, 0, stream>>>(Wl, Wp);

    k_conv1<35, 0><<<BSZ, 512, 0, stream>>>(src, wK1, t1K);
    k_conv2<35><<<BSZ, 512, 0, stream>>>(t1K, wK2, keyt);
    k_conv1<5, 40><<<BSZ, 512, 0, stream>>>(src, wQ1, t1Q);
    k_conv2<5><<<BSZ, 512, 0, stream>>>(t1Q, wQ2, qt);
    k_att<<<BSZ, 512, 0, stream>>>(qt, keyt, att);
    k_dctatt<<<BSZ, 256, 0, stream>>>(src, att, dct, dct_att, dct_in);

    for (int j = 0; j < 3; ++j) {
        k_h0<<<BSZ, 512, 0, stream>>>(dct_in, dct_att, Win + (size_t)j * VL * DM,
                                      j == 0 ? nullptr : hB, h0);
        for (int l = 0; l < 6; ++l) {
            k_amix<<<BSZ, 512, 0, stream>>>(Agcn + (size_t)j * NF * NF,
                                            l == 0 ? h0 : hB, h0, hA);
            k_gemm_tanh<<<dim3(264, 8), 256, 0, stream>>>(
                hA, Wp + (size_t)(j * 6 + l) * DM * DM, hB);
        }
        k_out<<<BSZ, 256, 0, stream>>>(hB, Wout + (size_t)j * DM * VL, dct, dct_in,
                                       out + (size_t)j * BSZ * VL * NF);
    }
}

// Round 2
// 2554.440 us; speedup vs baseline: 2.0161x; 2.0161x over previous
//
#include <hip/hip_runtime.h>
#include <hip/hip_bf16.h>
#include <math.h>

static constexpr int BSZ  = 256;
static constexpr int NF   = 66;
static constexpr int DM   = 512;
static constexpr int DCTN = 10;
static constexpr int VL   = 20;   // KS + output_n
static constexpr int NWIN = 31;   // vn

typedef __attribute__((ext_vector_type(8))) short bf16x8;
typedef __attribute__((ext_vector_type(4))) float f32x4;

__device__ __forceinline__ float tanh_fast(float x) {
    // tanh(x) = 1 - 2/(e^{2x}+1); exp2-based, saturates correctly at +-inf
    float e = __builtin_amdgcn_exp2f(x * 2.8853900817779268f);
    return 1.0f - 2.0f * __builtin_amdgcn_rcpf(e + 1.0f);
}

__device__ __forceinline__ void gl_lds16(const __hip_bfloat16* g, short* l) {
    __builtin_amdgcn_global_load_lds(
        (const __attribute__((address_space(1))) void*)g,
        (__attribute__((address_space(3))) void*)l, 16, 0, 0);
}

// ---------------- workspace layout (bytes) ----------------
static constexpr size_t B_DCT  = 0;                                  // 400 f32 (pad 4096)
static constexpr size_t B_H0   = 4096;                               // 16896*512 f32
static constexpr size_t B_KEYT = B_H0   + 34603008;                  // 256*31*512 f32
static constexpr size_t B_QT   = B_KEYT + 16252928;                  // 256*512 f32
static constexpr size_t B_DA   = B_QT   + 524288;                    // 256*660 f32
static constexpr size_t B_DI   = B_DA   + 675840;                    // 256*660 f32
static constexpr size_t B_ATT  = B_DI   + 675840;                    // 256*32 f32
static constexpr size_t B_WPT  = B_ATT  + 32768;                     // 18*512*512 bf16
static constexpr size_t B_WTK  = B_WPT  + 9437184;                   // 512*2560 bf16
static constexpr size_t B_WTQ  = B_WTK  + 2621440;                   // 512*2560 bf16
static constexpr size_t B_T1K  = B_WTQ  + 2621440;                   // 256*35*512 bf16
static constexpr size_t B_T1Q  = B_T1K  + 9175040;                   // 256*5*512 bf16
static constexpr size_t B_HA   = B_T1Q  + 1310720;                   // 16896*512 bf16
static constexpr size_t B_HB   = B_HA   + 17301504;                  // 16896*512 bf16
// end = B_HB + 17301504 ~= 110 MB

// ---------------- constant builders ----------------
__global__ void k_build_dct(float* __restrict__ dct) {
    int idx = threadIdx.x;
    if (idx < 400) {
        int k = idx / 20, i = idx % 20;
        double w = (k == 0) ? 0.22360679774997896 : 0.31622776601683794;
        dct[idx] = (float)(w * cos(3.14159265358979323846 * (i + 0.5) * k / 20.0));
    }
}

// WpT[mat][n][k] = bf16( beta*Wl[mat][k][n] + (1-beta)*(n==k) ), mat = j*6+l
__global__ __launch_bounds__(256) void k_build_wpT(const float* __restrict__ Wl,
                                                   __hip_bfloat16* __restrict__ WpT) {
    __shared__ float t[32][33];
    int mat = blockIdx.z;
    int l = mat % 6;
    float beta = logf(0.5f / (float)(l + 1) + 1.0f);
    int kb = blockIdx.x * 32, nb = blockIdx.y * 32;
    int tx = threadIdx.x & 31, ty = threadIdx.x >> 5;  // 32x8
    const float* Wm = Wl + (size_t)mat * DM * DM;
#pragma unroll
    for (int i = 0; i < 32; i += 8)
        t[ty + i][tx] = Wm[(size_t)(kb + ty + i) * DM + nb + tx];
    __syncthreads();
    __hip_bfloat16* Om = WpT + (size_t)mat * DM * DM;
#pragma unroll
    for (int i = 0; i < 32; i += 8) {
        int n = nb + ty + i, k = kb + tx;
        float v = beta * t[tx][ty + i] + ((n == k) ? (1.0f - beta) : 0.0f);
        Om[(size_t)n * DM + k] = (__hip_bfloat16)v;
    }
}

// wT[o][kk*512+i] = bf16(w2[o][i][kk])
__global__ __launch_bounds__(256) void k_build_wcT(const float* __restrict__ w,
                                                   __hip_bfloat16* __restrict__ wT) {
    int o = blockIdx.x;
    const float* wrow = w + (size_t)o * 2560;
    __hip_bfloat16* orow = wT + (size_t)o * 2560;
    for (int idx = threadIdx.x; idx < 2560; idx += 256) {
        int kk = idx >> 9, i = idx & 511;
        orow[idx] = (__hip_bfloat16)wrow[i * 5 + kk];
    }
}

// ---------------- conv1 (fp32 compute, bf16 out) ----------------
template<int T, int T0>
__global__ __launch_bounds__(512) void k_conv1(const float* __restrict__ src,
                                               const float* __restrict__ w,
                                               __hip_bfloat16* __restrict__ out) {
    __shared__ float s_src[50 * NF];
    int b = blockIdx.x;
    const float* sb = src + (size_t)b * 50 * NF;
    for (int i = threadIdx.x; i < 50 * NF; i += 512) s_src[i] = sb[i] * 1e-3f;
    __syncthreads();
    int o = threadIdx.x;
    float acc[T];
#pragma unroll
    for (int t = 0; t < T; ++t) acc[t] = 0.f;
    const float* wo = w + (size_t)o * (NF * 6);
    for (int i = 0; i < NF; ++i) {
#pragma unroll
        for (int k = 0; k < 6; ++k) {
            float wv = wo[i * 6 + k];
#pragma unroll
            for (int t = 0; t < T; ++t)
                acc[t] += s_src[(T0 + t + k) * NF + i] * wv;
        }
    }
    for (int t = 0; t < T; ++t)
        out[((size_t)b * T + t) * DM + o] = (__hip_bfloat16)fmaxf(acc[t], 0.f);
}

// ---------------- MFMA GEMM ----------------
// C[MxN] = epi(A' @ BT^T). A rows: r -> global row base ((r/TOUT)*TIN + r%TOUT)*512
// (plain GEMM: TIN=TOUT=1 and KTOT=512). BT row-major [N][KTOT] bf16.
// EPI 0: tanh -> bf16 ; EPI 1: relu -> f32
template<int TIN, int TOUT, int KTOT, int EPI>
__global__ __launch_bounds__(256) void k_gemm(const __hip_bfloat16* __restrict__ A,
                                              const __hip_bfloat16* __restrict__ BT,
                                              void* __restrict__ Cv) {
    __shared__ short sA[128 * 64];
    __shared__ short sB[128 * 64];
    const int tid = threadIdx.x;
    const int row0 = blockIdx.x * 128, col0 = blockIdx.y * 128;
    const int lane = tid & 63, wid = tid >> 6;
    const int wr = wid >> 1, wc = wid & 1;  // 2x2 waves, each 64x64 output

    // precompute per-thread staging pointers (source pre-swizzled: rule both-sides)
    const __hip_bfloat16* gA[4];
    const __hip_bfloat16* gB[4];
#pragma unroll
    for (int it = 0; it < 4; ++it) {
        int c = it * 256 + tid;          // chunk 0..1023, 16B each
        int r = c >> 3, c16 = c & 7;
        int s16 = c16 ^ (r & 7);
        int grow = row0 + r;
        gA[it] = A + ((size_t)(grow / TOUT) * TIN + (grow % TOUT)) * 512 + s16 * 8;
        gB[it] = BT + (size_t)(col0 + r) * KTOT + s16 * 8;
    }

    f32x4 acc[4][4] = {};
    for (int k0 = 0; k0 < KTOT; k0 += 64) {
#pragma unroll
        for (int it = 0; it < 4; ++it) {
            int c = it * 256 + tid;
            gl_lds16(gA[it] + k0, sA + c * 8);
            gl_lds16(gB[it] + k0, sB + c * 8);
        }
        __syncthreads();
#pragma unroll
        for (int kk = 0; kk < 2; ++kk) {
            bf16x8 af[4], bfr[4];
#pragma unroll
            for (int m = 0; m < 4; ++m) {
                int row = wr * 64 + m * 16 + (lane & 15);
                int c16 = (kk * 4 + (lane >> 4)) ^ (row & 7);
                af[m] = *(const bf16x8*)&sA[row * 64 + c16 * 8];
            }
#pragma unroll
            for (int n = 0; n < 4; ++n) {
                int row = wc * 64 + n * 16 + (lane & 15);
                int c16 = (kk * 4 + (lane >> 4)) ^ (row & 7);
                bfr[n] = *(const bf16x8*)&sB[row * 64 + c16 * 8];
            }
#pragma unroll
            for (int m = 0; m < 4; ++m)
#pragma unroll
                for (int n = 0; n < 4; ++n)
                    acc[m][n] = __builtin_amdgcn_mfma_f32_16x16x32_bf16(
                        af[m], bfr[n], acc[m][n], 0, 0, 0);
        }
        __syncthreads();
    }
    // epilogue: C/D layout col=lane&15, row=(lane>>4)*4+j
#pragma unroll
    for (int m = 0; m < 4; ++m) {
#pragma unroll
        for (int n = 0; n < 4; ++n) {
            int col = col0 + wc * 64 + n * 16 + (lane & 15);
#pragma unroll
            for (int j = 0; j < 4; ++j) {
                int row = row0 + wr * 64 + m * 16 + (lane >> 4) * 4 + j;
                float v = acc[m][n][j];
                if constexpr (EPI == 0) {
                    ((__hip_bfloat16*)Cv)[(size_t)row * DM + col] =
                        (__hip_bfloat16)tanh_fast(v);
                } else {
                    ((float*)Cv)[(size_t)row * DM + col] = fmaxf(v, 0.f);
                }
            }
        }
    }
}

// ---------------- attention ----------------
__global__ __launch_bounds__(512) void k_att(const float* __restrict__ qt,
                                             const float* __restrict__ keyt,
                                             float* __restrict__ att) {
    int b = blockIdx.x;
    __shared__ float s_sc[NWIN];
    int wave = threadIdx.x >> 6, lane = threadIdx.x & 63;
    const float* qp = qt + (size_t)b * DM;
    for (int k = wave; k < NWIN; k += 8) {
        const float* kp = keyt + ((size_t)b * NWIN + k) * DM;
        float p = 0.f;
        for (int d = lane; d < DM; d += 64) p += qp[d] * kp[d];
#pragma unroll
        for (int off = 32; off; off >>= 1) p += __shfl_down(p, off);
        if (lane == 0) s_sc[k] = p + 1e-15f;
    }
    __syncthreads();
    if (threadIdx.x == 0) {
        float s = 0.f;
        for (int k = 0; k < NWIN; ++k) s += s_sc[k];
        float inv = 1.f / s;
        for (int k = 0; k < NWIN; ++k) att[(size_t)b * 32 + k] = s_sc[k] * inv;
    }
}

__global__ __launch_bounds__(256) void k_dctatt(const float* __restrict__ src,
                                                const float* __restrict__ att,
                                                const float* __restrict__ dct,
                                                float* __restrict__ dct_att,
                                                float* __restrict__ dct_in) {
    int b = blockIdx.x;
    __shared__ float s_src[50 * NF];
    __shared__ float s_att[NWIN];
    __shared__ float s_ws[VL * NF];
    const float* sb = src + (size_t)b * 50 * NF;
    for (int i = threadIdx.x; i < 50 * NF; i += 256) s_src[i] = sb[i];
    if (threadIdx.x < NWIN) s_att[threadIdx.x] = att[(size_t)b * 32 + threadIdx.x];
    __syncthreads();
    for (int i = threadIdx.x; i < VL * NF; i += 256) {
        int l = i / NF, f = i % NF;
        float a = 0.f;
        for (int v = 0; v < NWIN; ++v) a += s_att[v] * s_src[(v + l) * NF + f];
        s_ws[i] = a;
    }
    __syncthreads();
    for (int i = threadIdx.x; i < NF * DCTN; i += 256) {
        int f = i / DCTN, d = i % DCTN;
        float a = 0.f, c = 0.f;
#pragma unroll
        for (int l = 0; l < VL; ++l) {
            float dm = dct[d * VL + l];
            a += dm * s_ws[l * NF + f];
            int t2 = (l < 10) ? (40 + l) : 49;
            c += dm * s_src[t2 * NF + f];
        }
        dct_att[(size_t)b * NF * DCTN + i] = a;
        dct_in[(size_t)b * NF * DCTN + i] = c;
    }
}

// ---------------- GCN small kernels ----------------
__global__ __launch_bounds__(512) void k_h0(const float* __restrict__ dct_in,
                                            const float* __restrict__ dct_att,
                                            const float* __restrict__ Win,
                                            const __hip_bfloat16* __restrict__ his,
                                            float* __restrict__ h0) {
    int b = blockIdx.x, d = threadIdx.x;
    __shared__ float s_x[NF * VL];
    for (int i = threadIdx.x; i < NF * DCTN; i += 512) {
        int f = i / DCTN, c = i % DCTN;
        s_x[f * VL + c]      = dct_in[(size_t)b * NF * DCTN + i];
        s_x[f * VL + 10 + c] = dct_att[(size_t)b * NF * DCTN + i];
    }
    __syncthreads();
    float w[VL];
#pragma unroll
    for (int c = 0; c < VL; ++c) w[c] = Win[c * DM + d];
    const __hip_bfloat16* hisb = his + (size_t)b * NF * DM + d;
    float* h0b = h0 + (size_t)b * NF * DM + d;
    for (int f = 0; f < NF; ++f) {
        float a = 0.f;
#pragma unroll
        for (int c = 0; c < VL; ++c) a += s_x[f * VL + c] * w[c];
        float v = tanh_fast(a);
        if (his) v += __bfloat162float(hisb[(size_t)f * DM]);
        h0b[(size_t)f * DM] = v;
    }
}

// m = bf16( 0.9 * A@h + 0.1 * h0 );  h from bf16 (hb) or f32 (hf)
__global__ __launch_bounds__(512) void k_amix(const float* __restrict__ A,
                                              const __hip_bfloat16* __restrict__ hb,
                                              const float* __restrict__ hf,
                                              const float* __restrict__ h0,
                                              __hip_bfloat16* __restrict__ m) {
    int b = blockIdx.x, d = threadIdx.x;
    float hreg[NF];
    if (hf) {
        const float* p = hf + (size_t)b * NF * DM + d;
#pragma unroll
        for (int mm = 0; mm < NF; ++mm) hreg[mm] = p[(size_t)mm * DM];
    } else {
        const __hip_bfloat16* p = hb + (size_t)b * NF * DM + d;
#pragma unroll
        for (int mm = 0; mm < NF; ++mm) hreg[mm] = __bfloat162float(p[(size_t)mm * DM]);
    }
    const float* h0b = h0 + (size_t)b * NF * DM + d;
    __hip_bfloat16* mb = m + (size_t)b * NF * DM + d;
    for (int n = 0; n < NF; ++n) {
        float a = 0.f;
        const float* An = A + n * NF;
#pragma unroll
        for (int mm = 0; mm < NF; ++mm) a += An[mm] * hreg[mm];
        mb[(size_t)n * DM] = (__hip_bfloat16)(0.9f * a + 0.1f * h0b[(size_t)n * DM]);
    }
}

__global__ __launch_bounds__(256) void k_out(const __hip_bfloat16* __restrict__ h,
                                             const float* __restrict__ Wout,
                                             const float* __restrict__ dct,
                                             float* __restrict__ dct_in,
                                             float* __restrict__ outj) {
    int b = blockIdx.x;
    __shared__ float s_do[NF * DCTN];
    int wave = threadIdx.x >> 6, lane = threadIdx.x & 63;
    const __hip_bfloat16* hb = h + (size_t)b * NF * DM;
    for (int i = wave; i < NF * DCTN; i += 4) {
        int f = i / DCTN, c = i % DCTN;
        float p = 0.f;
        for (int d = lane; d < DM; d += 64)
            p += __bfloat162float(hb[(size_t)f * DM + d]) * Wout[d * VL + c];
#pragma unroll
        for (int off = 32; off; off >>= 1) p += __shfl_down(p, off);
        if (lane == 0) s_do[i] = p + dct_in[(size_t)b * NF * DCTN + i];
    }
    __syncthreads();
    for (int i = threadIdx.x; i < NF * DCTN; i += 256)
        dct_in[(size_t)b * NF * DCTN + i] = s_do[i];
    for (int i = threadIdx.x; i < VL * NF; i += 256) {
        int l = i / NF, f = i % NF;
        float a = 0.f;
#pragma unroll
        for (int d = 0; d < DCTN; ++d) a += dct[d * VL + l] * s_do[f * DCTN + d];
        outj[((size_t)b * VL + l) * NF + f] = a;
    }
}

extern "C" void kernel_launch(void* const* d_in, const int* in_sizes, int n_in,
                              void* d_out, int out_size, void* d_ws, size_t ws_size,
                              hipStream_t stream) {
    const float* src  = (const float*)d_in[0];
    const float* wQ1  = (const float*)d_in[1];
    const float* wQ2  = (const float*)d_in[2];
    const float* wK1  = (const float*)d_in[3];
    const float* wK2  = (const float*)d_in[4];
    const float* Win  = (const float*)d_in[5];
    const float* Agcn = (const float*)d_in[6];
    const float* Wl   = (const float*)d_in[7];
    const float* Wout = (const float*)d_in[8];
    char* ws = (char*)d_ws;
    float* out = (float*)d_out;

    float* dct      = (float*)(ws + B_DCT);
    float* h0       = (float*)(ws + B_H0);
    float* keyt     = (float*)(ws + B_KEYT);
    float* qt       = (float*)(ws + B_QT);
    float* dct_att  = (float*)(ws + B_DA);
    float* dct_in   = (float*)(ws + B_DI);
    float* att      = (float*)(ws + B_ATT);
    __hip_bfloat16* WpT = (__hip_bfloat16*)(ws + B_WPT);
    __hip_bfloat16* wTK = (__hip_bfloat16*)(ws + B_WTK);
    __hip_bfloat16* wTQ = (__hip_bfloat16*)(ws + B_WTQ);
    __hip_bfloat16* t1K = (__hip_bfloat16*)(ws + B_T1K);
    __hip_bfloat16* t1Q = (__hip_bfloat16*)(ws + B_T1Q);
    __hip_bfloat16* hA  = (__hip_bfloat16*)(ws + B_HA);
    __hip_bfloat16* hB  = (__hip_bfloat16*)(ws + B_HB);

    k_build_dct<<<1, 512, 0, stream>>>(dct);
    k_build_wpT<<<dim3(16, 16, 18), 256, 0, stream>>>(Wl, WpT);
    k_build_wcT<<<512, 256, 0, stream>>>(wK2, wTK);
    k_build_wcT<<<512, 256, 0, stream>>>(wQ2, wTQ);

    k_conv1<35, 0><<<BSZ, 512, 0, stream>>>(src, wK1, t1K);
    k_gemm<35, 31, 2560, 1><<<dim3(62, 4), 256, 0, stream>>>(t1K, wTK, keyt);
    k_conv1<5, 40><<<BSZ, 512, 0, stream>>>(src, wQ1, t1Q);
    k_gemm<5, 1, 2560, 1><<<dim3(2, 4), 256, 0, stream>>>(t1Q, wTQ, qt);
    k_att<<<BSZ, 512, 0, stream>>>(qt, keyt, att);
    k_dctatt<<<BSZ, 256, 0, stream>>>(src, att, dct, dct_att, dct_in);

    for (int j = 0; j < 3; ++j) {
        k_h0<<<BSZ, 512, 0, stream>>>(dct_in, dct_att, Win + (size_t)j * VL * DM,
                                      j == 0 ? nullptr : hB, h0);
        for (int l = 0; l < 6; ++l) {
            k_amix<<<BSZ, 512, 0, stream>>>(Agcn + (size_t)j * NF * NF,
                                            hB, l == 0 ? h0 : nullptr, h0, hA);
            k_gemm<1, 1, 512, 0><<<dim3(132, 4), 256, 0, stream>>>(
                hA, WpT + (size_t)(j * 6 + l) * DM * DM, hB);
        }
        k_out<<<BSZ, 256, 0, stream>>>(hB, Wout + (size_t)j * DM * VL, dct, dct_in,
                                       out + (size_t)j * BSZ * VL * NF);
    }
}

// Round 5
// 1869.126 us; speedup vs baseline: 2.7553x; 1.3666x over previous
//
#include <hip/hip_runtime.h>
#include <hip/hip_bf16.h>
#include <math.h>

static constexpr int BSZ  = 256;
static constexpr int NF   = 66;
static constexpr int DM   = 512;
static constexpr int DCTN = 10;
static constexpr int VL   = 20;   // KS + output_n
static constexpr int NWIN = 31;   // vn

typedef __attribute__((ext_vector_type(8))) short bf16x8;
typedef __attribute__((ext_vector_type(4))) float f32x4;

__device__ __forceinline__ float tanh_fast(float x) {
    float e = __builtin_amdgcn_exp2f(x * 2.8853900817779268f);
    return 1.0f - 2.0f * __builtin_amdgcn_rcpf(e + 1.0f);
}

__device__ __forceinline__ void gl_lds16(const __hip_bfloat16* g, short* l) {
    __builtin_amdgcn_global_load_lds(
        (const __attribute__((address_space(1))) void*)g,
        (__attribute__((address_space(3))) void*)l, 16, 0, 0);
}

// ---------------- workspace layout (bytes) ----------------
static constexpr size_t B_DCT  = 0;                                   // 400 f32
static constexpr size_t B_KEYT = 4096;                                // 7936*512 f32
static constexpr size_t B_QT   = B_KEYT + 16252928;                   // 256*512 f32
static constexpr size_t B_DA   = B_QT   + 524288;                     // 256*660 f32
static constexpr size_t B_DI   = B_DA   + 675840;                     // 16896*10 f32
static constexpr size_t B_ATT  = B_DI   + 675840;                     // 256*32 f32
static constexpr size_t B_H0   = B_ATT  + 32768;                      // 16896*512 bf16
static constexpr size_t B_WPT  = B_H0   + 17301504;                   // 18*512*512 bf16
static constexpr size_t B_WTK  = B_WPT  + 9437184;                    // 512*2560 bf16
static constexpr size_t B_WTQ  = B_WTK  + 2621440;                    // 512*2560 bf16
static constexpr size_t B_W1K  = B_WTQ  + 2621440;                    // 512*448 bf16
static constexpr size_t B_W1Q  = B_W1K  + 458752;                     // 512*448 bf16
static constexpr size_t B_WOT  = B_W1Q  + 458752;                     // 3*16*512 bf16
static constexpr size_t B_SRCB = B_WOT  + 49152;                      // 256*50*72 bf16
static constexpr size_t B_T1K  = B_SRCB + 1843200;                    // 8960*512 bf16
static constexpr size_t B_T1Q  = B_T1K  + 9175040;                    // 1280*512 bf16
static constexpr size_t B_HA   = B_T1Q  + 1310720;                    // 16896*512 bf16
static constexpr size_t B_HB   = B_HA   + 17301504;                   // 16896*512 bf16
// end ~= 115.5 MB

// ---------------- constant builders ----------------
__global__ void k_build_dct(float* __restrict__ dct) {
    int idx = threadIdx.x;
    if (idx < 400) {
        int k = idx / 20, i = idx % 20;
        double w = (k == 0) ? 0.22360679774997896 : 0.31622776601683794;
        dct[idx] = (float)(w * cos(3.14159265358979323846 * (i + 0.5) * k / 20.0));
    }
}

__global__ __launch_bounds__(256) void k_build_wpT(const float* __restrict__ Wl,
                                                   __hip_bfloat16* __restrict__ WpT) {
    __shared__ float t[32][33];
    int mat = blockIdx.z;
    int l = mat % 6;
    float beta = logf(0.5f / (float)(l + 1) + 1.0f);
    int kb = blockIdx.x * 32, nb = blockIdx.y * 32;
    int tx = threadIdx.x & 31, ty = threadIdx.x >> 5;
    const float* Wm = Wl + (size_t)mat * DM * DM;
#pragma unroll
    for (int i = 0; i < 32; i += 8)
        t[ty + i][tx] = Wm[(size_t)(kb + ty + i) * DM + nb + tx];
    __syncthreads();
    __hip_bfloat16* Om = WpT + (size_t)mat * DM * DM;
#pragma unroll
    for (int i = 0; i < 32; i += 8) {
        int n = nb + ty + i, k = kb + tx;
        float v = beta * t[tx][ty + i] + ((n == k) ? (1.0f - beta) : 0.0f);
        Om[(size_t)n * DM + k] = (__hip_bfloat16)v;
    }
}

// conv2 weights: wT[o][kk*512+i] = w2[o][i][kk]
__global__ __launch_bounds__(256) void k_build_wcT(const float* __restrict__ w,
                                                   __hip_bfloat16* __restrict__ wT) {
    int o = blockIdx.x;
    const float* wrow = w + (size_t)o * 2560;
    __hip_bfloat16* orow = wT + (size_t)o * 2560;
    for (int idx = threadIdx.x; idx < 2560; idx += 256) {
        int kk = idx >> 9, i = idx & 511;
        orow[idx] = (__hip_bfloat16)wrow[i * 5 + kk];
    }
}

// conv1 weights padded: w1T[o][k'] ; k' = kk*72+i, zero in pad slots; K=448
__global__ __launch_bounds__(256) void k_build_w1T(const float* __restrict__ w,
                                                   __hip_bfloat16* __restrict__ wT) {
    int o = blockIdx.x;
    const float* wrow = w + (size_t)o * (NF * 6);
    __hip_bfloat16* orow = wT + (size_t)o * 448;
    for (int kp = threadIdx.x; kp < 448; kp += 256) {
        int kk = kp / 72, i = kp % 72;
        float v = (kk < 6 && i < NF) ? wrow[i * 6 + kk] : 0.f;
        orow[kp] = (__hip_bfloat16)v;
    }
}

// WoutT[j][n][k] = Wout[j][k][n] for n<10 else 0
__global__ __launch_bounds__(256) void k_build_woutT(const float* __restrict__ Wout,
                                                     __hip_bfloat16* __restrict__ WoT) {
    int j = blockIdx.x;
    const float* Wj = Wout + (size_t)j * DM * VL;
    __hip_bfloat16* Oj = WoT + (size_t)j * 16 * DM;
    for (int idx = threadIdx.x; idx < 16 * DM; idx += 256) {
        int n = idx >> 9, k = idx & 511;
        Oj[idx] = (__hip_bfloat16)((n < DCTN) ? Wj[k * VL + n] : 0.f);
    }
}

// scaled+padded src copy: srcb[b][t][i72] = (i<66) ? src[b][t][i]*1e-3 : 0
__global__ __launch_bounds__(256) void k_src_bf16(const float* __restrict__ src,
                                                  __hip_bfloat16* __restrict__ dst) {
    int row = blockIdx.x * 8 + (threadIdx.x >> 5);   // 12800 rows total
    int i = threadIdx.x & 31;
    const float* s = src + (size_t)row * NF;
    __hip_bfloat16* d = dst + (size_t)row * 72;
#pragma unroll
    for (int jj = 0; jj < 3; ++jj) {
        int c = i + jj * 32;
        if (c < 72) d[c] = (__hip_bfloat16)((c < NF) ? s[c] * 1e-3f : 0.f);
    }
}

// ---------------- generic MFMA GEMM ----------------
// A-row r maps to element offset (r/TOUT)*SROW + (r%TOUT)*SCOL + SOFF.
// BT row-major [N][KTOT] bf16. C row-major [M][512].
// EPI: 0 tanh->bf16 ; 1 relu->f32 ; 2 relu->bf16
template<int TOUT, size_t SROW, int SCOL, int SOFF, int KTOT, int EPI>
__global__ __launch_bounds__(256) void k_gemm(const __hip_bfloat16* __restrict__ A,
                                              const __hip_bfloat16* __restrict__ BT,
                                              void* __restrict__ Cv) {
    __shared__ short sA[128 * 64];
    __shared__ short sB[128 * 64];
    const int tid = threadIdx.x;
    const int row0 = blockIdx.x * 128, col0 = blockIdx.y * 128;
    const int lane = tid & 63, wid = tid >> 6;
    const int wr = wid >> 1, wc = wid & 1;

    const __hip_bfloat16* gA[4];
    const __hip_bfloat16* gB[4];
#pragma unroll
    for (int it = 0; it < 4; ++it) {
        int c = it * 256 + tid;
        int r = c >> 3, c16 = c & 7;
        int s16 = c16 ^ (r & 7);
        int grow = row0 + r;
        gA[it] = A + (size_t)(grow / TOUT) * SROW + (size_t)(grow % TOUT) * SCOL
                   + SOFF + s16 * 8;
        gB[it] = BT + (size_t)(col0 + r) * KTOT + s16 * 8;
    }

    f32x4 acc[4][4] = {};
    for (int k0 = 0; k0 < KTOT; k0 += 64) {
#pragma unroll
        for (int it = 0; it < 4; ++it) {
            int c = it * 256 + tid;
            gl_lds16(gA[it] + k0, sA + c * 8);
            gl_lds16(gB[it] + k0, sB + c * 8);
        }
        __syncthreads();
#pragma unroll
        for (int kk = 0; kk < 2; ++kk) {
            bf16x8 af[4], bfr[4];
#pragma unroll
            for (int m = 0; m < 4; ++m) {
                int row = wr * 64 + m * 16 + (lane & 15);
                int c16 = (kk * 4 + (lane >> 4)) ^ (row & 7);
                af[m] = *(const bf16x8*)&sA[row * 64 + c16 * 8];
            }
#pragma unroll
            for (int n = 0; n < 4; ++n) {
                int row = wc * 64 + n * 16 + (lane & 15);
                int c16 = (kk * 4 + (lane >> 4)) ^ (row & 7);
                bfr[n] = *(const bf16x8*)&sB[row * 64 + c16 * 8];
            }
#pragma unroll
            for (int m = 0; m < 4; ++m)
#pragma unroll
                for (int n = 0; n < 4; ++n)
                    acc[m][n] = __builtin_amdgcn_mfma_f32_16x16x32_bf16(
                        af[m], bfr[n], acc[m][n], 0, 0, 0);
        }
        __syncthreads();
    }
#pragma unroll
    for (int m = 0; m < 4; ++m) {
#pragma unroll
        for (int n = 0; n < 4; ++n) {
            int col = col0 + wc * 64 + n * 16 + (lane & 15);
#pragma unroll
            for (int j = 0; j < 4; ++j) {
                int row = row0 + wr * 64 + m * 16 + (lane >> 4) * 4 + j;
                float v = acc[m][n][j];
                if constexpr (EPI == 0) {
                    ((__hip_bfloat16*)Cv)[(size_t)row * DM + col] =
                        (__hip_bfloat16)tanh_fast(v);
                } else if constexpr (EPI == 1) {
                    ((float*)Cv)[(size_t)row * DM + col] = fmaxf(v, 0.f);
                } else {
                    ((__hip_bfloat16*)Cv)[(size_t)row * DM + col] =
                        (__hip_bfloat16)fmaxf(v, 0.f);
                }
            }
        }
    }
}

// ---------------- Wout MFMA: dct_in += h @ WoutT (N=16, 10 valid) ----------------
// 4 waves stacked over rows: each wave owns 32 rows (2 m-tiles of 16).
__global__ __launch_bounds__(256) void k_wout(const __hip_bfloat16* __restrict__ h,
                                              const __hip_bfloat16* __restrict__ woT,
                                              float* __restrict__ dct_in) {
    __shared__ short sA[128 * 64];
    __shared__ short sB[16 * 512];
    const int tid = threadIdx.x;
    const int row0 = blockIdx.x * 128;
    const int lane = tid & 63, wid = tid >> 6;

    // stage B (whole 16x512) once
#pragma unroll
    for (int it = 0; it < 4; ++it) {
        int c = it * 256 + tid;             // 1024 chunks
        int n = c >> 6, c16 = c & 63;
        int s16 = (c16 & 56) | ((c16 & 7) ^ (n & 7));
        gl_lds16(woT + (size_t)n * DM + s16 * 8, sB + c * 8);
    }
    const __hip_bfloat16* gA[4];
#pragma unroll
    for (int it = 0; it < 4; ++it) {
        int c = it * 256 + tid;
        int r = c >> 3, c16 = c & 7;
        gA[it] = h + (size_t)(row0 + r) * DM + (c16 ^ (r & 7)) * 8;
    }

    f32x4 acc[2] = {};
    for (int k0 = 0; k0 < DM; k0 += 64) {
#pragma unroll
        for (int it = 0; it < 4; ++it) {
            int c = it * 256 + tid;
            gl_lds16(gA[it] + k0, sA + c * 8);
        }
        __syncthreads();
#pragma unroll
        for (int kk = 0; kk < 2; ++kk) {
            bf16x8 bfr;
            {
                int n = lane & 15;
                int kb = (k0 >> 3) + kk * 4 + (lane >> 4);
                int slot = (kb & 56) | ((kb & 7) ^ (n & 7));
                bfr = *(const bf16x8*)&sB[n * DM + slot * 8];
            }
#pragma unroll
            for (int m = 0; m < 2; ++m) {
                int row = wid * 32 + m * 16 + (lane & 15);
                int c16 = (kk * 4 + (lane >> 4)) ^ (row & 7);
                bf16x8 af = *(const bf16x8*)&sA[row * 64 + c16 * 8];
                acc[m] = __builtin_amdgcn_mfma_f32_16x16x32_bf16(af, bfr, acc[m], 0, 0, 0);
            }
        }
        __syncthreads();
    }
    int col = lane & 15;
    if (col < DCTN) {
#pragma unroll
        for (int m = 0; m < 2; ++m) {
#pragma unroll
            for (int j = 0; j < 4; ++j) {
                int row = row0 + wid * 32 + m * 16 + (lane >> 4) * 4 + j;
                size_t o = (size_t)row * DCTN + col;
                dct_in[o] += acc[m][j];
            }
        }
    }
}

// idct per batch: out[b][l][f] = sum_d dct[d*20+l] * dct_in[b][f][d]
__global__ __launch_bounds__(256) void k_idct(const float* __restrict__ dct_in,
                                              const float* __restrict__ dct,
                                              float* __restrict__ outj) {
    int b = blockIdx.x;
    __shared__ float s_do[NF * DCTN];
    __shared__ float s_dct[400];
    for (int i = threadIdx.x; i < NF * DCTN; i += 256)
        s_do[i] = dct_in[(size_t)b * NF * DCTN + i];
    for (int i = threadIdx.x; i < 400; i += 256) s_dct[i] = dct[i];
    __syncthreads();
    for (int i = threadIdx.x; i < VL * NF; i += 256) {
        int l = i / NF, f = i % NF;
        float a = 0.f;
#pragma unroll
        for (int d = 0; d < DCTN; ++d) a += s_dct[d * VL + l] * s_do[f * DCTN + d];
        outj[((size_t)b * VL + l) * NF + f] = a;
    }
}

// ---------------- attention ----------------
__global__ __launch_bounds__(512) void k_att(const float* __restrict__ qt,
                                             const float* __restrict__ keyt,
                                             float* __restrict__ att) {
    int b = blockIdx.x;
    __shared__ float s_sc[NWIN];
    int wave = threadIdx.x >> 6, lane = threadIdx.x & 63;
    const float* qp = qt + (size_t)b * DM;
    for (int k = wave; k < NWIN; k += 8) {
        const float* kp = keyt + ((size_t)b * NWIN + k) * DM;
        float p = 0.f;
        for (int d = lane; d < DM; d += 64) p += qp[d] * kp[d];
#pragma unroll
        for (int off = 32; off; off >>= 1) p += __shfl_down(p, off);
        if (lane == 0) s_sc[k] = p + 1e-15f;
    }
    __syncthreads();
    if (threadIdx.x == 0) {
        float s = 0.f;
        for (int k = 0; k < NWIN; ++k) s += s_sc[k];
        float inv = 1.f / s;
        for (int k = 0; k < NWIN; ++k) att[(size_t)b * 32 + k] = s_sc[k] * inv;
    }
}

__global__ __launch_bounds__(256) void k_dctatt(const float* __restrict__ src,
                                                const float* __restrict__ att,
                                                const float* __restrict__ dct,
                                                float* __restrict__ dct_att,
                                                float* __restrict__ dct_in) {
    int b = blockIdx.x;
    __shared__ float s_src[50 * NF];
    __shared__ float s_att[NWIN];
    __shared__ float s_ws[VL * NF];
    const float* sb = src + (size_t)b * 50 * NF;
    for (int i = threadIdx.x; i < 50 * NF; i += 256) s_src[i] = sb[i];
    if (threadIdx.x < NWIN) s_att[threadIdx.x] = att[(size_t)b * 32 + threadIdx.x];
    __syncthreads();
    for (int i = threadIdx.x; i < VL * NF; i += 256) {
        int l = i / NF, f = i % NF;
        float a = 0.f;
        for (int v = 0; v < NWIN; ++v) a += s_att[v] * s_src[(v + l) * NF + f];
        s_ws[i] = a;
    }
    __syncthreads();
    for (int i = threadIdx.x; i < NF * DCTN; i += 256) {
        int f = i / DCTN, d = i % DCTN;
        float a = 0.f, c = 0.f;
#pragma unroll
        for (int l = 0; l < VL; ++l) {
            float dm = dct[d * VL + l];
            a += dm * s_ws[l * NF + f];
            int t2 = (l < 10) ? (40 + l) : 49;
            c += dm * s_src[t2 * NF + f];
        }
        dct_att[(size_t)b * NF * DCTN + i] = a;
        dct_in[(size_t)b * NF * DCTN + i] = c;
    }
}

// ---------------- GCN small kernels ----------------
__global__ __launch_bounds__(512) void k_h0(const float* __restrict__ dct_in,
                                            const float* __restrict__ dct_att,
                                            const float* __restrict__ Win,
                                            const __hip_bfloat16* __restrict__ his,
                                            __hip_bfloat16* __restrict__ h0) {
    int b = blockIdx.x, d = threadIdx.x;
    __shared__ float s_x[NF * VL];
    for (int i = threadIdx.x; i < NF * DCTN; i += 512) {
        int f = i / DCTN, c = i % DCTN;
        s_x[f * VL + c]      = dct_in[(size_t)b * NF * DCTN + i];
        s_x[f * VL + 10 + c] = dct_att[(size_t)b * NF * DCTN + i];
    }
    __syncthreads();
    float w[VL];
#pragma unroll
    for (int c = 0; c < VL; ++c) w[c] = Win[c * DM + d];
    const __hip_bfloat16* hisb = his + (size_t)b * NF * DM + d;
    __hip_bfloat16* h0b = h0 + (size_t)b * NF * DM + d;
    for (int f = 0; f < NF; ++f) {
        float a = 0.f;
#pragma unroll
        for (int c = 0; c < VL; ++c) a += s_x[f * VL + c] * w[c];
        float v = tanh_fast(a);
        if (his) v += __bfloat162float(hisb[(size_t)f * DM]);
        h0b[(size_t)f * DM] = (__hip_bfloat16)v;
    }
}

// m = bf16(0.9 * A@h + 0.1 * h0), all bf16 state
__global__ __launch_bounds__(512) void k_amix(const float* __restrict__ A,
                                              const __hip_bfloat16* __restrict__ h,
                                              const __hip_bfloat16* __restrict__ h0,
                                              __hip_bfloat16* __restrict__ m) {
    int b = blockIdx.x, d = threadIdx.x;
    float hreg[NF];
    const __hip_bfloat16* p = h + (size_t)b * NF * DM + d;
#pragma unroll
    for (int mm = 0; mm < NF; ++mm) hreg[mm] = __bfloat162float(p[(size_t)mm * DM]);
    const __hip_bfloat16* h0b = h0 + (size_t)b * NF * DM + d;
    __hip_bfloat16* mb = m + (size_t)b * NF * DM + d;
    for (int n = 0; n < NF; ++n) {
        float a = 0.f;
        const float* An = A + n * NF;
#pragma unroll
        for (int mm = 0; mm < NF; ++mm) a += An[mm] * hreg[mm];
        mb[(size_t)n * DM] =
            (__hip_bfloat16)(0.9f * a + 0.1f * __bfloat162float(h0b[(size_t)n * DM]));
    }
}

extern "C" void kernel_launch(void* const* d_in, const int* in_sizes, int n_in,
                              void* d_out, int out_size, void* d_ws, size_t ws_size,
                              hipStream_t stream) {
    const float* src  = (const float*)d_in[0];
    const float* wQ1  = (const float*)d_in[1];
    const float* wQ2  = (const float*)d_in[2];
    const float* wK1  = (const float*)d_in[3];
    const float* wK2  = (const float*)d_in[4];
    const float* Win  = (const float*)d_in[5];
    const float* Agcn = (const float*)d_in[6];
    const float* Wl   = (const float*)d_in[7];
    const float* Wout = (const float*)d_in[8];
    char* ws = (char*)d_ws;
    float* out = (float*)d_out;

    float* dct      = (float*)(ws + B_DCT);
    float* keyt     = (float*)(ws + B_KEYT);
    float* qt       = (float*)(ws + B_QT);
    float* dct_att  = (float*)(ws + B_DA);
    float* dct_in   = (float*)(ws + B_DI);
    float* att      = (float*)(ws + B_ATT);
    __hip_bfloat16* h0b = (__hip_bfloat16*)(ws + B_H0);
    __hip_bfloat16* WpT = (__hip_bfloat16*)(ws + B_WPT);
    __hip_bfloat16* wTK = (__hip_bfloat16*)(ws + B_WTK);
    __hip_bfloat16* wTQ = (__hip_bfloat16*)(ws + B_WTQ);
    __hip_bfloat16* w1K = (__hip_bfloat16*)(ws + B_W1K);
    __hip_bfloat16* w1Q = (__hip_bfloat16*)(ws + B_W1Q);
    __hip_bfloat16* woT = (__hip_bfloat16*)(ws + B_WOT);
    __hip_bfloat16* srcb= (__hip_bfloat16*)(ws + B_SRCB);
    __hip_bfloat16* t1K = (__hip_bfloat16*)(ws + B_T1K);
    __hip_bfloat16* t1Q = (__hip_bfloat16*)(ws + B_T1Q);
    __hip_bfloat16* hA  = (__hip_bfloat16*)(ws + B_HA);
    __hip_bfloat16* hB  = (__hip_bfloat16*)(ws + B_HB);

    k_build_dct<<<1, 512, 0, stream>>>(dct);
    k_build_wpT<<<dim3(16, 16, 18), 256, 0, stream>>>(Wl, WpT);
    k_build_wcT<<<512, 256, 0, stream>>>(wK2, wTK);
    k_build_wcT<<<512, 256, 0, stream>>>(wQ2, wTQ);
    k_build_w1T<<<512, 256, 0, stream>>>(wK1, w1K);
    k_build_w1T<<<512, 256, 0, stream>>>(wQ1, w1Q);
    k_build_woutT<<<3, 256, 0, stream>>>(Wout, woT);
    k_src_bf16<<<1600, 256, 0, stream>>>(src, srcb);

    // conv stacks as implicit GEMMs
    k_gemm<35, 3600, 72, 0,    448, 2><<<dim3(70, 4), 256, 0, stream>>>(srcb, w1K, t1K);
    k_gemm<31, 17920, 512, 0, 2560, 1><<<dim3(62, 4), 256, 0, stream>>>(t1K, wTK, keyt);
    k_gemm<5, 3600, 72, 2880,  448, 2><<<dim3(10, 4), 256, 0, stream>>>(srcb, w1Q, t1Q);
    k_gemm<1, 2560, 0, 0,     2560, 1><<<dim3(2, 4), 256, 0, stream>>>(t1Q, wTQ, qt);

    k_att<<<BSZ, 512, 0, stream>>>(qt, keyt, att);
    k_dctatt<<<BSZ, 256, 0, stream>>>(src, att, dct, dct_att, dct_in);

    for (int j = 0; j < 3; ++j) {
        k_h0<<<BSZ, 512, 0, stream>>>(dct_in, dct_att, Win + (size_t)j * VL * DM,
                                      j == 0 ? nullptr : hB, h0b);
        for (int l = 0; l < 6; ++l) {
            k_amix<<<BSZ, 512, 0, stream>>>(Agcn + (size_t)j * NF * NF,
                                            l == 0 ? h0b : hB, h0b, hA);
            k_gemm<1, 512, 0, 0, 512, 0><<<dim3(132, 4), 256, 0, stream>>>(
                hA, WpT + (size_t)(j * 6 + l) * DM * DM, hB);
        }
        k_wout<<<132, 256, 0, stream>>>(hB, woT + (size_t)j * 16 * DM, dct_in);
        k_idct<<<BSZ, 256, 0, stream>>>(dct_in, dct, out + (size_t)j * BSZ * VL * NF);
    }
}

// Round 7
// 1692.588 us; speedup vs baseline: 3.0427x; 1.1043x over previous
//
#include <hip/hip_runtime.h>
#include <hip/hip_bf16.h>
#include <math.h>

static constexpr int BSZ  = 256;
static constexpr int NF   = 66;
static constexpr int DM   = 512;
static constexpr int DCTN = 10;
static constexpr int VL   = 20;   // KS + output_n
static constexpr int NWIN = 31;   // vn

typedef __attribute__((ext_vector_type(8))) short bf16x8;
typedef __attribute__((ext_vector_type(4))) float f32x4;

__device__ __forceinline__ float tanh_fast(float x) {
    float e = __builtin_amdgcn_exp2f(x * 2.8853900817779268f);
    return 1.0f - 2.0f * __builtin_amdgcn_rcpf(e + 1.0f);
}

__device__ __forceinline__ void gl_lds16(const __hip_bfloat16* g, short* l) {
    __builtin_amdgcn_global_load_lds(
        (const __attribute__((address_space(1))) void*)g,
        (__attribute__((address_space(3))) void*)l, 16, 0, 0);
}

// ---------------- workspace layout (bytes) ----------------
static constexpr size_t B_DCT  = 0;                                   // 400 f32
static constexpr size_t B_KEYT = 4096;                                // 7936*512 f32
static constexpr size_t B_QT   = B_KEYT + 16252928;                   // 256*512 f32
static constexpr size_t B_DA   = B_QT   + 524288;                     // 256*660 f32
static constexpr size_t B_DI   = B_DA   + 675840;                     // 16896*10 f32
static constexpr size_t B_ATT  = B_DI   + 675840;                     // 256*32 f32
static constexpr size_t B_H0   = B_ATT  + 32768;                      // 16896*512 bf16
static constexpr size_t B_WPT  = B_H0   + 17301504;                   // 18*512*512 bf16
static constexpr size_t B_WTK  = B_WPT  + 9437184;                    // 512*2560 bf16
static constexpr size_t B_WTQ  = B_WTK  + 2621440;                    // 512*2560 bf16
static constexpr size_t B_W1K  = B_WTQ  + 2621440;                    // 512*448 bf16
static constexpr size_t B_W1Q  = B_W1K  + 458752;                     // 512*448 bf16
static constexpr size_t B_WOT  = B_W1Q  + 458752;                     // 3*16*512 bf16
static constexpr size_t B_SRCB = B_WOT  + 49152;                      // 256*50*72 bf16
static constexpr size_t B_T1K  = B_SRCB + 1843200;                    // 8960*512 bf16
static constexpr size_t B_T1Q  = B_T1K  + 9175040;                    // 1280*512 bf16
static constexpr size_t B_HA   = B_T1Q  + 1310720;                    // 16896*512 bf16
static constexpr size_t B_HB   = B_HA   + 17301504;                   // 16896*512 bf16
// end ~= 115.5 MB

// ---------------- constant builders ----------------
__global__ void k_build_dct(float* __restrict__ dct) {
    int idx = threadIdx.x;
    if (idx < 400) {
        int k = idx / 20, i = idx % 20;
        double w = (k == 0) ? 0.22360679774997896 : 0.31622776601683794;
        dct[idx] = (float)(w * cos(3.14159265358979323846 * (i + 0.5) * k / 20.0));
    }
}

__global__ __launch_bounds__(256) void k_build_wpT(const float* __restrict__ Wl,
                                                   __hip_bfloat16* __restrict__ WpT) {
    __shared__ float t[32][33];
    int mat = blockIdx.z;
    int l = mat % 6;
    float beta = logf(0.5f / (float)(l + 1) + 1.0f);
    int kb = blockIdx.x * 32, nb = blockIdx.y * 32;
    int tx = threadIdx.x & 31, ty = threadIdx.x >> 5;
    const float* Wm = Wl + (size_t)mat * DM * DM;
#pragma unroll
    for (int i = 0; i < 32; i += 8)
        t[ty + i][tx] = Wm[(size_t)(kb + ty + i) * DM + nb + tx];
    __syncthreads();
    __hip_bfloat16* Om = WpT + (size_t)mat * DM * DM;
#pragma unroll
    for (int i = 0; i < 32; i += 8) {
        int n = nb + ty + i, k = kb + tx;
        float v = beta * t[tx][ty + i] + ((n == k) ? (1.0f - beta) : 0.0f);
        Om[(size_t)n * DM + k] = (__hip_bfloat16)v;
    }
}

// conv2 weights: wT[o][kk*512+i] = w2[o][i][kk]
__global__ __launch_bounds__(256) void k_build_wcT(const float* __restrict__ w,
                                                   __hip_bfloat16* __restrict__ wT) {
    int o = blockIdx.x;
    const float* wrow = w + (size_t)o * 2560;
    __hip_bfloat16* orow = wT + (size_t)o * 2560;
    for (int idx = threadIdx.x; idx < 2560; idx += 256) {
        int kk = idx >> 9, i = idx & 511;
        orow[idx] = (__hip_bfloat16)wrow[i * 5 + kk];
    }
}

// conv1 weights padded: w1T[o][k'] ; k' = kk*72+i, zero in pad slots; K=448
__global__ __launch_bounds__(256) void k_build_w1T(const float* __restrict__ w,
                                                   __hip_bfloat16* __restrict__ wT) {
    int o = blockIdx.x;
    const float* wrow = w + (size_t)o * (NF * 6);
    __hip_bfloat16* orow = wT + (size_t)o * 448;
    for (int kp = threadIdx.x; kp < 448; kp += 256) {
        int kk = kp / 72, i = kp % 72;
        float v = (kk < 6 && i < NF) ? wrow[i * 6 + kk] : 0.f;
        orow[kp] = (__hip_bfloat16)v;
    }
}

// WoutT[j][n][k] = Wout[j][k][n] for n<10 else 0
__global__ __launch_bounds__(256) void k_build_woutT(const float* __restrict__ Wout,
                                                     __hip_bfloat16* __restrict__ WoT) {
    int j = blockIdx.x;
    const float* Wj = Wout + (size_t)j * DM * VL;
    __hip_bfloat16* Oj = WoT + (size_t)j * 16 * DM;
    for (int idx = threadIdx.x; idx < 16 * DM; idx += 256) {
        int n = idx >> 9, k = idx & 511;
        Oj[idx] = (__hip_bfloat16)((n < DCTN) ? Wj[k * VL + n] : 0.f);
    }
}

// scaled+padded src copy: srcb[b][t][i72] = (i<66) ? src[b][t][i]*1e-3 : 0
__global__ __launch_bounds__(256) void k_src_bf16(const float* __restrict__ src,
                                                  __hip_bfloat16* __restrict__ dst) {
    int row = blockIdx.x * 8 + (threadIdx.x >> 5);   // 12800 rows total
    int i = threadIdx.x & 31;
    const float* s = src + (size_t)row * NF;
    __hip_bfloat16* d = dst + (size_t)row * 72;
#pragma unroll
    for (int jj = 0; jj < 3; ++jj) {
        int c = i + jj * 32;
        if (c < 72) d[c] = (__hip_bfloat16)((c < NF) ? s[c] * 1e-3f : 0.f);
    }
}

// ---------------- generic MFMA GEMM ----------------
// A-row r maps to element offset (r/TOUT)*SROW + (r%TOUT)*SCOL + SOFF.
// BT row-major [N][KTOT] bf16. C row-major [M][512].
// EPI: 0 tanh->bf16 ; 1 relu->f32 ; 2 relu->bf16
template<int TOUT, size_t SROW, int SCOL, int SOFF, int KTOT, int EPI>
__global__ __launch_bounds__(256) void k_gemm(const __hip_bfloat16* __restrict__ A,
                                              const __hip_bfloat16* __restrict__ BT,
                                              void* __restrict__ Cv) {
    __shared__ short sA[128 * 64];
    __shared__ short sB[128 * 64];
    const int tid = threadIdx.x;
    const int row0 = blockIdx.x * 128, col0 = blockIdx.y * 128;
    const int lane = tid & 63, wid = tid >> 6;
    const int wr = wid >> 1, wc = wid & 1;

    const __hip_bfloat16* gA[4];
    const __hip_bfloat16* gB[4];
#pragma unroll
    for (int it = 0; it < 4; ++it) {
        int c = it * 256 + tid;
        int r = c >> 3, c16 = c & 7;
        int s16 = c16 ^ (r & 7);
        int grow = row0 + r;
        gA[it] = A + (size_t)(grow / TOUT) * SROW + (size_t)(grow % TOUT) * SCOL
                   + SOFF + s16 * 8;
        gB[it] = BT + (size_t)(col0 + r) * KTOT + s16 * 8;
    }

    f32x4 acc[4][4] = {};
    for (int k0 = 0; k0 < KTOT; k0 += 64) {
#pragma unroll
        for (int it = 0; it < 4; ++it) {
            int c = it * 256 + tid;
            gl_lds16(gA[it] + k0, sA + c * 8);
            gl_lds16(gB[it] + k0, sB + c * 8);
        }
        __syncthreads();
#pragma unroll
        for (int kk = 0; kk < 2; ++kk) {
            bf16x8 af[4], bfr[4];
#pragma unroll
            for (int m = 0; m < 4; ++m) {
                int row = wr * 64 + m * 16 + (lane & 15);
                int c16 = (kk * 4 + (lane >> 4)) ^ (row & 7);
                af[m] = *(const bf16x8*)&sA[row * 64 + c16 * 8];
            }
#pragma unroll
            for (int n = 0; n < 4; ++n) {
                int row = wc * 64 + n * 16 + (lane & 15);
                int c16 = (kk * 4 + (lane >> 4)) ^ (row & 7);
                bfr[n] = *(const bf16x8*)&sB[row * 64 + c16 * 8];
            }
#pragma unroll
            for (int m = 0; m < 4; ++m)
#pragma unroll
                for (int n = 0; n < 4; ++n)
                    acc[m][n] = __builtin_amdgcn_mfma_f32_16x16x32_bf16(
                        af[m], bfr[n], acc[m][n], 0, 0, 0);
        }
        __syncthreads();
    }
#pragma unroll
    for (int m = 0; m < 4; ++m) {
#pragma unroll
        for (int n = 0; n < 4; ++n) {
            int col = col0 + wc * 64 + n * 16 + (lane & 15);
#pragma unroll
            for (int j = 0; j < 4; ++j) {
                int row = row0 + wr * 64 + m * 16 + (lane >> 4) * 4 + j;
                float v = acc[m][n][j];
                if constexpr (EPI == 0) {
                    ((__hip_bfloat16*)Cv)[(size_t)row * DM + col] =
                        (__hip_bfloat16)tanh_fast(v);
                } else if constexpr (EPI == 1) {
                    ((float*)Cv)[(size_t)row * DM + col] = fmaxf(v, 0.f);
                } else {
                    ((__hip_bfloat16*)Cv)[(size_t)row * DM + col] =
                        (__hip_bfloat16)fmaxf(v, 0.f);
                }
            }
        }
    }
}

// ---------------- Wout MFMA: dct_in += h @ WoutT (N=16, 10 valid) ----------------
// 4 waves stacked over rows: each wave owns 32 rows (2 m-tiles of 16).
__global__ __launch_bounds__(256) void k_wout(const __hip_bfloat16* __restrict__ h,
                                              const __hip_bfloat16* __restrict__ woT,
                                              float* __restrict__ dct_in) {
    __shared__ short sA[128 * 64];
    __shared__ short sB[16 * 512];
    const int tid = threadIdx.x;
    const int row0 = blockIdx.x * 128;
    const int lane = tid & 63, wid = tid >> 6;

    // stage B (whole 16x512) once
#pragma unroll
    for (int it = 0; it < 4; ++it) {
        int c = it * 256 + tid;             // 1024 chunks
        int n = c >> 6, c16 = c & 63;
        int s16 = (c16 & 56) | ((c16 & 7) ^ (n & 7));
        gl_lds16(woT + (size_t)n * DM + s16 * 8, sB + c * 8);
    }
    const __hip_bfloat16* gA[4];
#pragma unroll
    for (int it = 0; it < 4; ++it) {
        int c = it * 256 + tid;
        int r = c >> 3, c16 = c & 7;
        gA[it] = h + (size_t)(row0 + r) * DM + (c16 ^ (r & 7)) * 8;
    }

    f32x4 acc[2] = {};
    for (int k0 = 0; k0 < DM; k0 += 64) {
#pragma unroll
        for (int it = 0; it < 4; ++it) {
            int c = it * 256 + tid;
            gl_lds16(gA[it] + k0, sA + c * 8);
        }
        __syncthreads();
#pragma unroll
        for (int kk = 0; kk < 2; ++kk) {
            bf16x8 bfr;
            {
                int n = lane & 15;
                int kb = (k0 >> 3) + kk * 4 + (lane >> 4);
                int slot = (kb & 56) | ((kb & 7) ^ (n & 7));
                bfr = *(const bf16x8*)&sB[n * DM + slot * 8];
            }
#pragma unroll
            for (int m = 0; m < 2; ++m) {
                int row = wid * 32 + m * 16 + (lane & 15);
                int c16 = (kk * 4 + (lane >> 4)) ^ (row & 7);
                bf16x8 af = *(const bf16x8*)&sA[row * 64 + c16 * 8];
                acc[m] = __builtin_amdgcn_mfma_f32_16x16x32_bf16(af, bfr, acc[m], 0, 0, 0);
            }
        }
        __syncthreads();
    }
    int col = lane & 15;
    if (col < DCTN) {
#pragma unroll
        for (int m = 0; m < 2; ++m) {
#pragma unroll
            for (int j = 0; j < 4; ++j) {
                int row = row0 + wid * 32 + m * 16 + (lane >> 4) * 4 + j;
                size_t o = (size_t)row * DCTN + col;
                dct_in[o] += acc[m][j];
            }
        }
    }
}

// idct per batch: out[b][l][f] = sum_d dct[d*20+l] * dct_in[b][f][d]
__global__ __launch_bounds__(256) void k_idct(const float* __restrict__ dct_in,
                                              const float* __restrict__ dct,
                                              float* __restrict__ outj) {
    int b = blockIdx.x;
    __shared__ float s_do[NF * DCTN];
    __shared__ float s_dct[400];
    for (int i = threadIdx.x; i < NF * DCTN; i += 256)
        s_do[i] = dct_in[(size_t)b * NF * DCTN + i];
    for (int i = threadIdx.x; i < 400; i += 256) s_dct[i] = dct[i];
    __syncthreads();
    for (int i = threadIdx.x; i < VL * NF; i += 256) {
        int l = i / NF, f = i % NF;
        float a = 0.f;
#pragma unroll
        for (int d = 0; d < DCTN; ++d) a += s_dct[d * VL + l] * s_do[f * DCTN + d];
        outj[((size_t)b * VL + l) * NF + f] = a;
    }
}

// ---------------- attention ----------------
__global__ __launch_bounds__(512) void k_att(const float* __restrict__ qt,
                                             const float* __restrict__ keyt,
                                             float* __restrict__ att) {
    int b = blockIdx.x;
    __shared__ float s_sc[NWIN];
    int wave = threadIdx.x >> 6, lane = threadIdx.x & 63;
    const float* qp = qt + (size_t)b * DM;
    for (int k = wave; k < NWIN; k += 8) {
        const float* kp = keyt + ((size_t)b * NWIN + k) * DM;
        float p = 0.f;
        for (int d = lane; d < DM; d += 64) p += qp[d] * kp[d];
#pragma unroll
        for (int off = 32; off; off >>= 1) p += __shfl_down(p, off);
        if (lane == 0) s_sc[k] = p + 1e-15f;
    }
    __syncthreads();
    if (threadIdx.x == 0) {
        float s = 0.f;
        for (int k = 0; k < NWIN; ++k) s += s_sc[k];
        float inv = 1.f / s;
        for (int k = 0; k < NWIN; ++k) att[(size_t)b * 32 + k] = s_sc[k] * inv;
    }
}

__global__ __launch_bounds__(256) void k_dctatt(const float* __restrict__ src,
                                                const float* __restrict__ att,
                                                const float* __restrict__ dct,
                                                float* __restrict__ dct_att,
                                                float* __restrict__ dct_in) {
    int b = blockIdx.x;
    __shared__ float s_src[50 * NF];
    __shared__ float s_att[NWIN];
    __shared__ float s_ws[VL * NF];
    const float* sb = src + (size_t)b * 50 * NF;
    for (int i = threadIdx.x; i < 50 * NF; i += 256) s_src[i] = sb[i];
    if (threadIdx.x < NWIN) s_att[threadIdx.x] = att[(size_t)b * 32 + threadIdx.x];
    __syncthreads();
    for (int i = threadIdx.x; i < VL * NF; i += 256) {
        int l = i / NF, f = i % NF;
        float a = 0.f;
        for (int v = 0; v < NWIN; ++v) a += s_att[v] * s_src[(v + l) * NF + f];
        s_ws[i] = a;
    }
    __syncthreads();
    for (int i = threadIdx.x; i < NF * DCTN; i += 256) {
        int f = i / DCTN, d = i % DCTN;
        float a = 0.f, c = 0.f;
#pragma unroll
        for (int l = 0; l < VL; ++l) {
            float dm = dct[d * VL + l];
            a += dm * s_ws[l * NF + f];
            int t2 = (l < 10) ? (40 + l) : 49;
            c += dm * s_src[t2 * NF + f];
        }
        dct_att[(size_t)b * NF * DCTN + i] = a;
        dct_in[(size_t)b * NF * DCTN + i] = c;
    }
}

// ---------------- GCN small kernels ----------------
// f-split 2-way for occupancy (grid.y = 2, 33 f-rows per block)
__global__ __launch_bounds__(512) void k_h0(const float* __restrict__ dct_in,
                                            const float* __restrict__ dct_att,
                                            const float* __restrict__ Win,
                                            const __hip_bfloat16* __restrict__ his,
                                            __hip_bfloat16* __restrict__ h0) {
    int b = blockIdx.x, d = threadIdx.x;
    int f0 = blockIdx.y * 33;
    __shared__ float s_x[33 * VL];
    for (int i = threadIdx.x; i < 33 * DCTN; i += 512) {
        int f = i / DCTN, c = i % DCTN;
        size_t gi = (size_t)b * NF * DCTN + (size_t)(f0 + f) * DCTN + c;
        s_x[f * VL + c]      = dct_in[gi];
        s_x[f * VL + 10 + c] = dct_att[gi];
    }
    __syncthreads();
    float w[VL];
#pragma unroll
    for (int c = 0; c < VL; ++c) w[c] = Win[c * DM + d];
    const __hip_bfloat16* hisb = his + (size_t)b * NF * DM + (size_t)f0 * DM + d;
    __hip_bfloat16* h0b = h0 + (size_t)b * NF * DM + (size_t)f0 * DM + d;
    for (int f = 0; f < 33; ++f) {
        float a = 0.f;
#pragma unroll
        for (int c = 0; c < VL; ++c) a += s_x[f * VL + c] * w[c];
        float v = tanh_fast(a);
        if (his) v += __bfloat162float(hisb[(size_t)f * DM]);
        h0b[(size_t)f * DM] = (__hip_bfloat16)v;
    }
}

// m = bf16(0.9 * A@h + 0.1 * h0), all bf16 state.
// n-split 3-way (grid.y = 3, 22 n-rows per block) to lift occupancy
// from 2 waves/SIMD to 6 (wave count was pinned at (b*d)/64 = 2048).
__global__ __launch_bounds__(512) void k_amix(const float* __restrict__ A,
                                              const __hip_bfloat16* __restrict__ h,
                                              const __hip_bfloat16* __restrict__ h0,
                                              __hip_bfloat16* __restrict__ m) {
    int b = blockIdx.x, d = threadIdx.x;
    int n0 = blockIdx.y * 22;
    float hreg[NF];
    const __hip_bfloat16* p = h + (size_t)b * NF * DM + d;
#pragma unroll
    for (int mm = 0; mm < NF; ++mm) hreg[mm] = __bfloat162float(p[(size_t)mm * DM]);
    const __hip_bfloat16* h0b = h0 + (size_t)b * NF * DM + d;
    __hip_bfloat16* mb = m + (size_t)b * NF * DM + d;
    for (int n = n0; n < n0 + 22; ++n) {
        float a = 0.f;
        const float* An = A + n * NF;
#pragma unroll
        for (int mm = 0; mm < NF; ++mm) a += An[mm] * hreg[mm];
        mb[(size_t)n * DM] =
            (__hip_bfloat16)(0.9f * a + 0.1f * __bfloat162float(h0b[(size_t)n * DM]));
    }
}

extern "C" void kernel_launch(void* const* d_in, const int* in_sizes, int n_in,
                              void* d_out, int out_size, void* d_ws, size_t ws_size,
                              hipStream_t stream) {
    const float* src  = (const float*)d_in[0];
    const float* wQ1  = (const float*)d_in[1];
    const float* wQ2  = (const float*)d_in[2];
    const float* wK1  = (const float*)d_in[3];
    const float* wK2  = (const float*)d_in[4];
    const float* Win  = (const float*)d_in[5];
    const float* Agcn = (const float*)d_in[6];
    const float* Wl   = (const float*)d_in[7];
    const float* Wout = (const float*)d_in[8];
    char* ws = (char*)d_ws;
    float* out = (float*)d_out;

    float* dct      = (float*)(ws + B_DCT);
    float* keyt     = (float*)(ws + B_KEYT);
    float* qt       = (float*)(ws + B_QT);
    float* dct_att  = (float*)(ws + B_DA);
    float* dct_in   = (float*)(ws + B_DI);
    float* att      = (float*)(ws + B_ATT);
    __hip_bfloat16* h0b = (__hip_bfloat16*)(ws + B_H0);
    __hip_bfloat16* WpT = (__hip_bfloat16*)(ws + B_WPT);
    __hip_bfloat16* wTK = (__hip_bfloat16*)(ws + B_WTK);
    __hip_bfloat16* wTQ = (__hip_bfloat16*)(ws + B_WTQ);
    __hip_bfloat16* w1K = (__hip_bfloat16*)(ws + B_W1K);
    __hip_bfloat16* w1Q = (__hip_bfloat16*)(ws + B_W1Q);
    __hip_bfloat16* woT = (__hip_bfloat16*)(ws + B_WOT);
    __hip_bfloat16* srcb= (__hip_bfloat16*)(ws + B_SRCB);
    __hip_bfloat16* t1K = (__hip_bfloat16*)(ws + B_T1K);
    __hip_bfloat16* t1Q = (__hip_bfloat16*)(ws + B_T1Q);
    __hip_bfloat16* hA  = (__hip_bfloat16*)(ws + B_HA);
    __hip_bfloat16* hB  = (__hip_bfloat16*)(ws + B_HB);

    k_build_dct<<<1, 512, 0, stream>>>(dct);
    k_build_wpT<<<dim3(16, 16, 18), 256, 0, stream>>>(Wl, WpT);
    k_build_wcT<<<512, 256, 0, stream>>>(wK2, wTK);
    k_build_wcT<<<512, 256, 0, stream>>>(wQ2, wTQ);
    k_build_w1T<<<512, 256, 0, stream>>>(wK1, w1K);
    k_build_w1T<<<512, 256, 0, stream>>>(wQ1, w1Q);
    k_build_woutT<<<3, 256, 0, stream>>>(Wout, woT);
    k_src_bf16<<<1600, 256, 0, stream>>>(src, srcb);

    // conv stacks as implicit GEMMs
    k_gemm<35, 3600, 72, 0,    448, 2><<<dim3(70, 4), 256, 0, stream>>>(srcb, w1K, t1K);
    k_gemm<31, 17920, 512, 0, 2560, 1><<<dim3(62, 4), 256, 0, stream>>>(t1K, wTK, keyt);
    k_gemm<5, 3600, 72, 2880,  448, 2><<<dim3(10, 4), 256, 0, stream>>>(srcb, w1Q, t1Q);
    k_gemm<1, 2560, 0, 0,     2560, 1><<<dim3(2, 4), 256, 0, stream>>>(t1Q, wTQ, qt);

    k_att<<<BSZ, 512, 0, stream>>>(qt, keyt, att);
    k_dctatt<<<BSZ, 256, 0, stream>>>(src, att, dct, dct_att, dct_in);

    for (int j = 0; j < 3; ++j) {
        k_h0<<<dim3(BSZ, 2), 512, 0, stream>>>(dct_in, dct_att,
                                               Win + (size_t)j * VL * DM,
                                               j == 0 ? nullptr : hB, h0b);
        for (int l = 0; l < 6; ++l) {
            k_amix<<<dim3(BSZ, 3), 512, 0, stream>>>(Agcn + (size_t)j * NF * NF,
                                                     l == 0 ? h0b : hB, h0b, hA);
            k_gemm<1, 512, 0, 0, 512, 0><<<dim3(132, 4), 256, 0, stream>>>(
                hA, WpT + (size_t)(j * 6 + l) * DM * DM, hB);
        }
        k_wout<<<132, 256, 0, stream>>>(hB, woT + (size_t)j * 16 * DM, dct_in);
        k_idct<<<BSZ, 256, 0, stream>>>(dct_in, dct, out + (size_t)j * BSZ * VL * NF);
    }
}

// Round 9
// 1621.739 us; speedup vs baseline: 3.1757x; 1.0437x over previous
//
#include <hip/hip_runtime.h>
#include <hip/hip_bf16.h>
#include <math.h>

static constexpr int BSZ  = 256;
static constexpr int NF   = 66;
static constexpr int DM   = 512;
static constexpr int DCTN = 10;
static constexpr int VL   = 20;   // KS + output_n
static constexpr int NWIN = 31;   // vn

typedef __attribute__((ext_vector_type(8))) short bf16x8;
typedef __attribute__((ext_vector_type(4))) float f32x4;

__device__ __forceinline__ float tanh_fast(float x) {
    float e = __builtin_amdgcn_exp2f(x * 2.8853900817779268f);
    return 1.0f - 2.0f * __builtin_amdgcn_rcpf(e + 1.0f);
}

__device__ __forceinline__ void gl_lds16(const __hip_bfloat16* g, short* l) {
    __builtin_amdgcn_global_load_lds(
        (const __attribute__((address_space(1))) void*)g,
        (__attribute__((address_space(3))) void*)l, 16, 0, 0);
}

// ---------------- workspace layout (bytes) ----------------
static constexpr size_t B_DCT  = 0;                                   // 400 f32
static constexpr size_t B_KEYT = 4096;                                // 7936*512 f32
static constexpr size_t B_QT   = B_KEYT + 16252928;                   // 256*512 f32
static constexpr size_t B_DA   = B_QT   + 524288;                     // 256*660 f32
static constexpr size_t B_DI   = B_DA   + 675840;                     // 16896*10 f32
static constexpr size_t B_ATT  = B_DI   + 675840;                     // 256*32 f32
static constexpr size_t B_H0   = B_ATT  + 32768;                      // 16896*512 bf16
static constexpr size_t B_WPT  = B_H0   + 17301504;                   // 18*512*512 bf16
static constexpr size_t B_WTK  = B_WPT  + 9437184;                    // 512*2560 bf16
static constexpr size_t B_WTQ  = B_WTK  + 2621440;                    // 512*2560 bf16
static constexpr size_t B_W1K  = B_WTQ  + 2621440;                    // 512*448 bf16
static constexpr size_t B_W1Q  = B_W1K  + 458752;                     // 512*448 bf16
static constexpr size_t B_WOT  = B_W1Q  + 458752;                     // 3*16*512 bf16
static constexpr size_t B_SRCB = B_WOT  + 49152;                      // 256*50*72 bf16
static constexpr size_t B_T1K  = B_SRCB + 1843200;                    // 8960*512 bf16
static constexpr size_t B_T1Q  = B_T1K  + 9175040;                    // 1280*512 bf16
static constexpr size_t B_HA   = B_T1Q  + 1310720;                    // 16896*512 bf16
static constexpr size_t B_HB   = B_HA   + 17301504;                   // 16896*512 bf16
// end ~= 115.5 MB

// ---------------- constant builders ----------------
__global__ void k_build_dct(float* __restrict__ dct) {
    int idx = threadIdx.x;
    if (idx < 400) {
        int k = idx / 20, i = idx % 20;
        double w = (k == 0) ? 0.22360679774997896 : 0.31622776601683794;
        dct[idx] = (float)(w * cos(3.14159265358979323846 * (i + 0.5) * k / 20.0));
    }
}

__global__ __launch_bounds__(256) void k_build_wpT(const float* __restrict__ Wl,
                                                   __hip_bfloat16* __restrict__ WpT) {
    __shared__ float t[32][33];
    int mat = blockIdx.z;
    int l = mat % 6;
    float beta = logf(0.5f / (float)(l + 1) + 1.0f);
    int kb = blockIdx.x * 32, nb = blockIdx.y * 32;
    int tx = threadIdx.x & 31, ty = threadIdx.x >> 5;
    const float* Wm = Wl + (size_t)mat * DM * DM;
#pragma unroll
    for (int i = 0; i < 32; i += 8)
        t[ty + i][tx] = Wm[(size_t)(kb + ty + i) * DM + nb + tx];
    __syncthreads();
    __hip_bfloat16* Om = WpT + (size_t)mat * DM * DM;
#pragma unroll
    for (int i = 0; i < 32; i += 8) {
        int n = nb + ty + i, k = kb + tx;
        float v = beta * t[tx][ty + i] + ((n == k) ? (1.0f - beta) : 0.0f);
        Om[(size_t)n * DM + k] = (__hip_bfloat16)v;
    }
}

// conv2 weights: wT[o][kk*512+i] = w2[o][i][kk]
__global__ __launch_bounds__(256) void k_build_wcT(const float* __restrict__ w,
                                                   __hip_bfloat16* __restrict__ wT) {
    int o = blockIdx.x;
    const float* wrow = w + (size_t)o * 2560;
    __hip_bfloat16* orow = wT + (size_t)o * 2560;
    for (int idx = threadIdx.x; idx < 2560; idx += 256) {
        int kk = idx >> 9, i = idx & 511;
        orow[idx] = (__hip_bfloat16)wrow[i * 5 + kk];
    }
}

// conv1 weights padded: w1T[o][k'] ; k' = kk*72+i, zero in pad slots; K=448
__global__ __launch_bounds__(256) void k_build_w1T(const float* __restrict__ w,
                                                   __hip_bfloat16* __restrict__ wT) {
    int o = blockIdx.x;
    const float* wrow = w + (size_t)o * (NF * 6);
    __hip_bfloat16* orow = wT + (size_t)o * 448;
    for (int kp = threadIdx.x; kp < 448; kp += 256) {
        int kk = kp / 72, i = kp % 72;
        float v = (kk < 6 && i < NF) ? wrow[i * 6 + kk] : 0.f;
        orow[kp] = (__hip_bfloat16)v;
    }
}

// WoutT[j][n][k] = Wout[j][k][n] for n<10 else 0
__global__ __launch_bounds__(256) void k_build_woutT(const float* __restrict__ Wout,
                                                     __hip_bfloat16* __restrict__ WoT) {
    int j = blockIdx.x;
    const float* Wj = Wout + (size_t)j * DM * VL;
    __hip_bfloat16* Oj = WoT + (size_t)j * 16 * DM;
    for (int idx = threadIdx.x; idx < 16 * DM; idx += 256) {
        int n = idx >> 9, k = idx & 511;
        Oj[idx] = (__hip_bfloat16)((n < DCTN) ? Wj[k * VL + n] : 0.f);
    }
}

// scaled+padded src copy: srcb[b][t][i72] = (i<66) ? src[b][t][i]*1e-3 : 0
__global__ __launch_bounds__(256) void k_src_bf16(const float* __restrict__ src,
                                                  __hip_bfloat16* __restrict__ dst) {
    int row = blockIdx.x * 8 + (threadIdx.x >> 5);   // 12800 rows total
    int i = threadIdx.x & 31;
    const float* s = src + (size_t)row * NF;
    __hip_bfloat16* d = dst + (size_t)row * 72;
#pragma unroll
    for (int jj = 0; jj < 3; ++jj) {
        int c = i + jj * 32;
        if (c < 72) d[c] = (__hip_bfloat16)((c < NF) ? s[c] * 1e-3f : 0.f);
    }
}

// ---------------- generic MFMA GEMM ----------------
// A-row r maps to element offset (r/TOUT)*SROW + (r%TOUT)*SCOL + SOFF.
// BT row-major [N][KTOT] bf16. C row-major [M][512].
// EPI: 0 tanh->bf16 ; 1 relu->f32 ; 2 relu->bf16
template<int TOUT, size_t SROW, int SCOL, int SOFF, int KTOT, int EPI>
__global__ __launch_bounds__(256) void k_gemm(const __hip_bfloat16* __restrict__ A,
                                              const __hip_bfloat16* __restrict__ BT,
                                              void* __restrict__ Cv) {
    __shared__ short sA[128 * 64];
    __shared__ short sB[128 * 64];
    const int tid = threadIdx.x;
    const int row0 = blockIdx.x * 128, col0 = blockIdx.y * 128;
    const int lane = tid & 63, wid = tid >> 6;
    const int wr = wid >> 1, wc = wid & 1;

    const __hip_bfloat16* gA[4];
    const __hip_bfloat16* gB[4];
#pragma unroll
    for (int it = 0; it < 4; ++it) {
        int c = it * 256 + tid;
        int r = c >> 3, c16 = c & 7;
        int s16 = c16 ^ (r & 7);
        int grow = row0 + r;
        gA[it] = A + (size_t)(grow / TOUT) * SROW + (size_t)(grow % TOUT) * SCOL
                   + SOFF + s16 * 8;
        gB[it] = BT + (size_t)(col0 + r) * KTOT + s16 * 8;
    }

    f32x4 acc[4][4] = {};
    for (int k0 = 0; k0 < KTOT; k0 += 64) {
#pragma unroll
        for (int it = 0; it < 4; ++it) {
            int c = it * 256 + tid;
            gl_lds16(gA[it] + k0, sA + c * 8);
            gl_lds16(gB[it] + k0, sB + c * 8);
        }
        __syncthreads();
#pragma unroll
        for (int kk = 0; kk < 2; ++kk) {
            bf16x8 af[4], bfr[4];
#pragma unroll
            for (int m = 0; m < 4; ++m) {
                int row = wr * 64 + m * 16 + (lane & 15);
                int c16 = (kk * 4 + (lane >> 4)) ^ (row & 7);
                af[m] = *(const bf16x8*)&sA[row * 64 + c16 * 8];
            }
#pragma unroll
            for (int n = 0; n < 4; ++n) {
                int row = wc * 64 + n * 16 + (lane & 15);
                int c16 = (kk * 4 + (lane >> 4)) ^ (row & 7);
                bfr[n] = *(const bf16x8*)&sB[row * 64 + c16 * 8];
            }
#pragma unroll
            for (int m = 0; m < 4; ++m)
#pragma unroll
                for (int n = 0; n < 4; ++n)
                    acc[m][n] = __builtin_amdgcn_mfma_f32_16x16x32_bf16(
                        af[m], bfr[n], acc[m][n], 0, 0, 0);
        }
        __syncthreads();
    }
#pragma unroll
    for (int m = 0; m < 4; ++m) {
#pragma unroll
        for (int n = 0; n < 4; ++n) {
            int col = col0 + wc * 64 + n * 16 + (lane & 15);
#pragma unroll
            for (int j = 0; j < 4; ++j) {
                int row = row0 + wr * 64 + m * 16 + (lane >> 4) * 4 + j;
                float v = acc[m][n][j];
                if constexpr (EPI == 0) {
                    ((__hip_bfloat16*)Cv)[(size_t)row * DM + col] =
                        (__hip_bfloat16)tanh_fast(v);
                } else if constexpr (EPI == 1) {
                    ((float*)Cv)[(size_t)row * DM + col] = fmaxf(v, 0.f);
                } else {
                    ((__hip_bfloat16*)Cv)[(size_t)row * DM + col] =
                        (__hip_bfloat16)fmaxf(v, 0.f);
                }
            }
        }
    }
}

// ---------------- Wout MFMA: dct_in += h @ WoutT (N=16, 10 valid) ----------------
// 4 waves stacked over rows: each wave owns 32 rows (2 m-tiles of 16).
__global__ __launch_bounds__(256) void k_wout(const __hip_bfloat16* __restrict__ h,
                                              const __hip_bfloat16* __restrict__ woT,
                                              float* __restrict__ dct_in) {
    __shared__ short sA[128 * 64];
    __shared__ short sB[16 * 512];
    const int tid = threadIdx.x;
    const int row0 = blockIdx.x * 128;
    const int lane = tid & 63, wid = tid >> 6;

    // stage B (whole 16x512) once
#pragma unroll
    for (int it = 0; it < 4; ++it) {
        int c = it * 256 + tid;             // 1024 chunks
        int n = c >> 6, c16 = c & 63;
        int s16 = (c16 & 56) | ((c16 & 7) ^ (n & 7));
        gl_lds16(woT + (size_t)n * DM + s16 * 8, sB + c * 8);
    }
    const __hip_bfloat16* gA[4];
#pragma unroll
    for (int it = 0; it < 4; ++it) {
        int c = it * 256 + tid;
        int r = c >> 3, c16 = c & 7;
        gA[it] = h + (size_t)(row0 + r) * DM + (c16 ^ (r & 7)) * 8;
    }

    f32x4 acc[2] = {};
    for (int k0 = 0; k0 < DM; k0 += 64) {
#pragma unroll
        for (int it = 0; it < 4; ++it) {
            int c = it * 256 + tid;
            gl_lds16(gA[it] + k0, sA + c * 8);
        }
        __syncthreads();
#pragma unroll
        for (int kk = 0; kk < 2; ++kk) {
            bf16x8 bfr;
            {
                int n = lane & 15;
                int kb = (k0 >> 3) + kk * 4 + (lane >> 4);
                int slot = (kb & 56) | ((kb & 7) ^ (n & 7));
                bfr = *(const bf16x8*)&sB[n * DM + slot * 8];
            }
#pragma unroll
            for (int m = 0; m < 2; ++m) {
                int row = wid * 32 + m * 16 + (lane & 15);
                int c16 = (kk * 4 + (lane >> 4)) ^ (row & 7);
                bf16x8 af = *(const bf16x8*)&sA[row * 64 + c16 * 8];
                acc[m] = __builtin_amdgcn_mfma_f32_16x16x32_bf16(af, bfr, acc[m], 0, 0, 0);
            }
        }
        __syncthreads();
    }
    int col = lane & 15;
    if (col < DCTN) {
#pragma unroll
        for (int m = 0; m < 2; ++m) {
#pragma unroll
            for (int j = 0; j < 4; ++j) {
                int row = row0 + wid * 32 + m * 16 + (lane >> 4) * 4 + j;
                size_t o = (size_t)row * DCTN + col;
                dct_in[o] += acc[m][j];
            }
        }
    }
}

// idct per batch: out[b][l][f] = sum_d dct[d*20+l] * dct_in[b][f][d]
__global__ __launch_bounds__(256) void k_idct(const float* __restrict__ dct_in,
                                              const float* __restrict__ dct,
                                              float* __restrict__ outj) {
    int b = blockIdx.x;
    __shared__ float s_do[NF * DCTN];
    __shared__ float s_dct[400];
    for (int i = threadIdx.x; i < NF * DCTN; i += 256)
        s_do[i] = dct_in[(size_t)b * NF * DCTN + i];
    for (int i = threadIdx.x; i < 400; i += 256) s_dct[i] = dct[i];
    __syncthreads();
    for (int i = threadIdx.x; i < VL * NF; i += 256) {
        int l = i / NF, f = i % NF;
        float a = 0.f;
#pragma unroll
        for (int d = 0; d < DCTN; ++d) a += s_dct[d * VL + l] * s_do[f * DCTN + d];
        outj[((size_t)b * VL + l) * NF + f] = a;
    }
}

// ---------------- attention ----------------
__global__ __launch_bounds__(512) void k_att(const float* __restrict__ qt,
                                             const float* __restrict__ keyt,
                                             float* __restrict__ att) {
    int b = blockIdx.x;
    __shared__ float s_sc[NWIN];
    int wave = threadIdx.x >> 6, lane = threadIdx.x & 63;
    const float* qp = qt + (size_t)b * DM;
    for (int k = wave; k < NWIN; k += 8) {
        const float* kp = keyt + ((size_t)b * NWIN + k) * DM;
        float p = 0.f;
        for (int d = lane; d < DM; d += 64) p += qp[d] * kp[d];
#pragma unroll
        for (int off = 32; off; off >>= 1) p += __shfl_down(p, off);
        if (lane == 0) s_sc[k] = p + 1e-15f;
    }
    __syncthreads();
    if (threadIdx.x == 0) {
        float s = 0.f;
        for (int k = 0; k < NWIN; ++k) s += s_sc[k];
        float inv = 1.f / s;
        for (int k = 0; k < NWIN; ++k) att[(size_t)b * 32 + k] = s_sc[k] * inv;
    }
}

__global__ __launch_bounds__(256) void k_dctatt(const float* __restrict__ src,
                                                const float* __restrict__ att,
                                                const float* __restrict__ dct,
                                                float* __restrict__ dct_att,
                                                float* __restrict__ dct_in) {
    int b = blockIdx.x;
    __shared__ float s_src[50 * NF];
    __shared__ float s_att[NWIN];
    __shared__ float s_ws[VL * NF];
    const float* sb = src + (size_t)b * 50 * NF;
    for (int i = threadIdx.x; i < 50 * NF; i += 256) s_src[i] = sb[i];
    if (threadIdx.x < NWIN) s_att[threadIdx.x] = att[(size_t)b * 32 + threadIdx.x];
    __syncthreads();
    for (int i = threadIdx.x; i < VL * NF; i += 256) {
        int l = i / NF, f = i % NF;
        float a = 0.f;
        for (int v = 0; v < NWIN; ++v) a += s_att[v] * s_src[(v + l) * NF + f];
        s_ws[i] = a;
    }
    __syncthreads();
    for (int i = threadIdx.x; i < NF * DCTN; i += 256) {
        int f = i / DCTN, d = i % DCTN;
        float a = 0.f, c = 0.f;
#pragma unroll
        for (int l = 0; l < VL; ++l) {
            float dm = dct[d * VL + l];
            a += dm * s_ws[l * NF + f];
            int t2 = (l < 10) ? (40 + l) : 49;
            c += dm * s_src[t2 * NF + f];
        }
        dct_att[(size_t)b * NF * DCTN + i] = a;
        dct_in[(size_t)b * NF * DCTN + i] = c;
    }
}

// ---------------- GCN small kernels ----------------
// f-split 2-way for occupancy (grid.y = 2, 33 f-rows per block)
__global__ __launch_bounds__(512) void k_h0(const float* __restrict__ dct_in,
                                            const float* __restrict__ dct_att,
                                            const float* __restrict__ Win,
                                            const __hip_bfloat16* __restrict__ his,
                                            __hip_bfloat16* __restrict__ h0) {
    int b = blockIdx.x, d = threadIdx.x;
    int f0 = blockIdx.y * 33;
    __shared__ float s_x[33 * VL];
    for (int i = threadIdx.x; i < 33 * DCTN; i += 512) {
        int f = i / DCTN, c = i % DCTN;
        size_t gi = (size_t)b * NF * DCTN + (size_t)(f0 + f) * DCTN + c;
        s_x[f * VL + c]      = dct_in[gi];
        s_x[f * VL + 10 + c] = dct_att[gi];
    }
    __syncthreads();
    float w[VL];
#pragma unroll
    for (int c = 0; c < VL; ++c) w[c] = Win[c * DM + d];
    const __hip_bfloat16* hisb = his + (size_t)b * NF * DM + (size_t)f0 * DM + d;
    __hip_bfloat16* h0b = h0 + (size_t)b * NF * DM + (size_t)f0 * DM + d;
    for (int f = 0; f < 33; ++f) {
        float a = 0.f;
#pragma unroll
        for (int c = 0; c < VL; ++c) a += s_x[f * VL + c] * w[c];
        float v = tanh_fast(a);
        if (his) v += __bfloat162float(hisb[(size_t)f * DM]);
        h0b[(size_t)f * DM] = (__hip_bfloat16)v;
    }
}

// m = bf16(0.9 * A@h + 0.1 * h0).
// LDS-staged h: block = (b, 256-col d-chunk); h[b][66][dchunk] staged once via
// global_load_lds (33.8 KB), hot loop reads LDS only (R7 post-mortem: the old
// version was L3-latency-bound on 66 scattered 1KB-strided reads; n-split x3
// re-read h 3x and didn't help). A stays fp32 uniform (scalar loads).
__global__ __launch_bounds__(256) void k_amix(const float* __restrict__ A,
                                              const __hip_bfloat16* __restrict__ h,
                                              const __hip_bfloat16* __restrict__ h0,
                                              __hip_bfloat16* __restrict__ m) {
    __shared__ short sH[NF * 256];          // 33792 B
    const int b = blockIdx.x, d0 = blockIdx.y * 256, tid = threadIdx.x;
    const __hip_bfloat16* hb = h + (size_t)b * NF * DM + d0;
    // stage: 66 rows x 256 bf16 = 2112 chunks of 16B
#pragma unroll
    for (int it = 0; it < 9; ++it) {
        int c = it * 256 + tid;
        if (c < NF * 32) {
            int r = c >> 5, s = c & 31;
            gl_lds16(hb + (size_t)r * DM + s * 8, sH + c * 8);
        }
    }
    __syncthreads();
    float hreg[NF];
#pragma unroll
    for (int mm = 0; mm < NF; ++mm) {
        unsigned short u = ((const unsigned short*)sH)[mm * 256 + tid];
        unsigned int w = ((unsigned int)u) << 16;
        hreg[mm] = __builtin_bit_cast(float, w);
    }
    const __hip_bfloat16* h0b = h0 + (size_t)b * NF * DM + d0 + tid;
    __hip_bfloat16* mb = m + (size_t)b * NF * DM + d0 + tid;
    for (int n = 0; n < NF; ++n) {
        float a = 0.f;
        const float* An = A + n * NF;
#pragma unroll
        for (int mm = 0; mm < NF; ++mm) a += An[mm] * hreg[mm];
        mb[(size_t)n * DM] =
            (__hip_bfloat16)(0.9f * a + 0.1f * __bfloat162float(h0b[(size_t)n * DM]));
    }
}

extern "C" void kernel_launch(void* const* d_in, const int* in_sizes, int n_in,
                              void* d_out, int out_size, void* d_ws, size_t ws_size,
                              hipStream_t stream) {
    const float* src  = (const float*)d_in[0];
    const float* wQ1  = (const float*)d_in[1];
    const float* wQ2  = (const float*)d_in[2];
    const float* wK1  = (const float*)d_in[3];
    const float* wK2  = (const float*)d_in[4];
    const float* Win  = (const float*)d_in[5];
    const float* Agcn = (const float*)d_in[6];
    const float* Wl   = (const float*)d_in[7];
    const float* Wout = (const float*)d_in[8];
    char* ws = (char*)d_ws;
    float* out = (float*)d_out;

    float* dct      = (float*)(ws + B_DCT);
    float* keyt     = (float*)(ws + B_KEYT);
    float* qt       = (float*)(ws + B_QT);
    float* dct_att  = (float*)(ws + B_DA);
    float* dct_in   = (float*)(ws + B_DI);
    float* att      = (float*)(ws + B_ATT);
    __hip_bfloat16* h0b = (__hip_bfloat16*)(ws + B_H0);
    __hip_bfloat16* WpT = (__hip_bfloat16*)(ws + B_WPT);
    __hip_bfloat16* wTK = (__hip_bfloat16*)(ws + B_WTK);
    __hip_bfloat16* wTQ = (__hip_bfloat16*)(ws + B_WTQ);
    __hip_bfloat16* w1K = (__hip_bfloat16*)(ws + B_W1K);
    __hip_bfloat16* w1Q = (__hip_bfloat16*)(ws + B_W1Q);
    __hip_bfloat16* woT = (__hip_bfloat16*)(ws + B_WOT);
    __hip_bfloat16* srcb= (__hip_bfloat16*)(ws + B_SRCB);
    __hip_bfloat16* t1K = (__hip_bfloat16*)(ws + B_T1K);
    __hip_bfloat16* t1Q = (__hip_bfloat16*)(ws + B_T1Q);
    __hip_bfloat16* hA  = (__hip_bfloat16*)(ws + B_HA);
    __hip_bfloat16* hB  = (__hip_bfloat16*)(ws + B_HB);

    k_build_dct<<<1, 512, 0, stream>>>(dct);
    k_build_wpT<<<dim3(16, 16, 18), 256, 0, stream>>>(Wl, WpT);
    k_build_wcT<<<512, 256, 0, stream>>>(wK2, wTK);
    k_build_wcT<<<512, 256, 0, stream>>>(wQ2, wTQ);
    k_build_w1T<<<512, 256, 0, stream>>>(wK1, w1K);
    k_build_w1T<<<512, 256, 0, stream>>>(wQ1, w1Q);
    k_build_woutT<<<3, 256, 0, stream>>>(Wout, woT);
    k_src_bf16<<<1600, 256, 0, stream>>>(src, srcb);

    // conv stacks as implicit GEMMs
    k_gemm<35, 3600, 72, 0,    448, 2><<<dim3(70, 4), 256, 0, stream>>>(srcb, w1K, t1K);
    k_gemm<31, 17920, 512, 0, 2560, 1><<<dim3(62, 4), 256, 0, stream>>>(t1K, wTK, keyt);
    k_gemm<5, 3600, 72, 2880,  448, 2><<<dim3(10, 4), 256, 0, stream>>>(srcb, w1Q, t1Q);
    k_gemm<1, 2560, 0, 0,     2560, 1><<<dim3(2, 4), 256, 0, stream>>>(t1Q, wTQ, qt);

    k_att<<<BSZ, 512, 0, stream>>>(qt, keyt, att);
    k_dctatt<<<BSZ, 256, 0, stream>>>(src, att, dct, dct_att, dct_in);

    for (int j = 0; j < 3; ++j) {
        k_h0<<<dim3(BSZ, 2), 512, 0, stream>>>(dct_in, dct_att,
                                               Win + (size_t)j * VL * DM,
                                               j == 0 ? nullptr : hB, h0b);
        for (int l = 0; l < 6; ++l) {
            k_amix<<<dim3(BSZ, 2), 256, 0, stream>>>(Agcn + (size_t)j * NF * NF,
                                                     l == 0 ? h0b : hB, h0b, hA);
            k_gemm<1, 512, 0, 0, 512, 0><<<dim3(132, 4), 256, 0, stream>>>(
                hA, WpT + (size_t)(j * 6 + l) * DM * DM, hB);
        }
        k_wout<<<132, 256, 0, stream>>>(hB, woT + (size_t)j * 16 * DM, dct_in);
        k_idct<<<BSZ, 256, 0, stream>>>(dct_in, dct, out + (size_t)j * BSZ * VL * NF);
    }
}

// Round 10
// 981.782 us; speedup vs baseline: 5.2456x; 1.6518x over previous
//
#include <hip/hip_runtime.h>
#include <hip/hip_bf16.h>
#include <math.h>

static constexpr int BSZ  = 256;
static constexpr int NF   = 66;
static constexpr int DM   = 512;
static constexpr int DCTN = 10;
static constexpr int VL   = 20;   // KS + output_n
static constexpr int NWIN = 31;   // vn

typedef __attribute__((ext_vector_type(8))) short bf16x8;
typedef __attribute__((ext_vector_type(4))) float f32x4;

__device__ __forceinline__ float tanh_fast(float x) {
    float e = __builtin_amdgcn_exp2f(x * 2.8853900817779268f);
    return 1.0f - 2.0f * __builtin_amdgcn_rcpf(e + 1.0f);
}

__device__ __forceinline__ void gl_lds16(const __hip_bfloat16* g, short* l) {
    __builtin_amdgcn_global_load_lds(
        (const __attribute__((address_space(1))) void*)g,
        (__attribute__((address_space(3))) void*)l, 16, 0, 0);
}

__device__ __forceinline__ __hip_bfloat16 f2bf(float v) { return (__hip_bfloat16)v; }

// ---------------- workspace layout (bytes) ----------------
static constexpr size_t B_DCT  = 0;                                   // 400 f32
static constexpr size_t B_KEYT = 4096;                                // 7936*512 f32
static constexpr size_t B_QT   = B_KEYT + 16252928;                   // 256*512 f32
static constexpr size_t B_DA   = B_QT   + 524288;                     // 256*660 f32
static constexpr size_t B_DI   = B_DA   + 675840;                     // 16896*10 f32
static constexpr size_t B_ATT  = B_DI   + 675840;                     // 256*32 f32
static constexpr size_t B_H0   = B_ATT  + 32768;                      // 16896*512 bf16
static constexpr size_t B_WPT  = B_H0   + 17301504;                   // 18*512*512 bf16
static constexpr size_t B_WTK  = B_WPT  + 9437184;                    // 512*2560 bf16
static constexpr size_t B_WTQ  = B_WTK  + 2621440;                    // 512*2560 bf16
static constexpr size_t B_W1K  = B_WTQ  + 2621440;                    // 512*448 bf16
static constexpr size_t B_W1Q  = B_W1K  + 458752;                     // 512*448 bf16
static constexpr size_t B_WOT  = B_W1Q  + 458752;                     // 3*16*512 bf16
static constexpr size_t B_SRCB = B_WOT  + 49152;                      // 256*50*72 bf16
static constexpr size_t B_T1K  = B_SRCB + 1843200;                    // 8960*512 bf16
static constexpr size_t B_T1Q  = B_T1K  + 9175040;                    // 1280*512 bf16
static constexpr size_t B_HA   = B_T1Q  + 1310720;                    // 16896*512 bf16
static constexpr size_t B_HB   = B_HA   + 17301504;                   // 16896*512 bf16
static constexpr size_t B_AB   = B_HB   + 17301504;                   // 3*80*96 bf16 (padded A)
// end ~= 115.6 MB

// ---------------- constant builders ----------------
__global__ void k_build_dct(float* __restrict__ dct) {
    int idx = threadIdx.x;
    if (idx < 400) {
        int k = idx / 20, i = idx % 20;
        double w = (k == 0) ? 0.22360679774997896 : 0.31622776601683794;
        dct[idx] = (float)(w * cos(3.14159265358979323846 * (i + 0.5) * k / 20.0));
    }
}

__global__ __launch_bounds__(256) void k_build_wpT(const float* __restrict__ Wl,
                                                   __hip_bfloat16* __restrict__ WpT) {
    __shared__ float t[32][33];
    int mat = blockIdx.z;
    int l = mat % 6;
    float beta = logf(0.5f / (float)(l + 1) + 1.0f);
    int kb = blockIdx.x * 32, nb = blockIdx.y * 32;
    int tx = threadIdx.x & 31, ty = threadIdx.x >> 5;
    const float* Wm = Wl + (size_t)mat * DM * DM;
#pragma unroll
    for (int i = 0; i < 32; i += 8)
        t[ty + i][tx] = Wm[(size_t)(kb + ty + i) * DM + nb + tx];
    __syncthreads();
    __hip_bfloat16* Om = WpT + (size_t)mat * DM * DM;
#pragma unroll
    for (int i = 0; i < 32; i += 8) {
        int n = nb + ty + i, k = kb + tx;
        float v = beta * t[tx][ty + i] + ((n == k) ? (1.0f - beta) : 0.0f);
        Om[(size_t)n * DM + k] = f2bf(v);
    }
}

// conv2 weights: wT[o][kk*512+i] = w2[o][i][kk]
__global__ __launch_bounds__(256) void k_build_wcT(const float* __restrict__ w,
                                                   __hip_bfloat16* __restrict__ wT) {
    int o = blockIdx.x;
    const float* wrow = w + (size_t)o * 2560;
    __hip_bfloat16* orow = wT + (size_t)o * 2560;
    for (int idx = threadIdx.x; idx < 2560; idx += 256) {
        int kk = idx >> 9, i = idx & 511;
        orow[idx] = f2bf(wrow[i * 5 + kk]);
    }
}

// conv1 weights padded: w1T[o][k'] ; k' = kk*72+i, zero in pad slots; K=448
__global__ __launch_bounds__(256) void k_build_w1T(const float* __restrict__ w,
                                                   __hip_bfloat16* __restrict__ wT) {
    int o = blockIdx.x;
    const float* wrow = w + (size_t)o * (NF * 6);
    __hip_bfloat16* orow = wT + (size_t)o * 448;
    for (int kp = threadIdx.x; kp < 448; kp += 256) {
        int kk = kp / 72, i = kp % 72;
        float v = (kk < 6 && i < NF) ? wrow[i * 6 + kk] : 0.f;
        orow[kp] = f2bf(v);
    }
}

// WoutT[j][n][k] = Wout[j][k][n] for n<10 else 0
__global__ __launch_bounds__(256) void k_build_woutT(const float* __restrict__ Wout,
                                                     __hip_bfloat16* __restrict__ WoT) {
    int j = blockIdx.x;
    const float* Wj = Wout + (size_t)j * DM * VL;
    __hip_bfloat16* Oj = WoT + (size_t)j * 16 * DM;
    for (int idx = threadIdx.x; idx < 16 * DM; idx += 256) {
        int n = idx >> 9, k = idx & 511;
        Oj[idx] = f2bf((n < DCTN) ? Wj[k * VL + n] : 0.f);
    }
}

// graph matrix padded to bf16 [80][96]: Ab[j][n][k] = A[j][n][k] (n,k<66) else 0
__global__ __launch_bounds__(256) void k_build_ab(const float* __restrict__ Agcn,
                                                  __hip_bfloat16* __restrict__ Ab) {
    int j = blockIdx.x;
    const float* Aj = Agcn + (size_t)j * NF * NF;
    __hip_bfloat16* Oj = Ab + (size_t)j * 80 * 96;
    for (int idx = threadIdx.x; idx < 80 * 96; idx += 256) {
        int n = idx / 96, k = idx % 96;
        Oj[idx] = f2bf((n < NF && k < NF) ? Aj[n * NF + k] : 0.f);
    }
}

// scaled+padded src copy: srcb[b][t][i72] = (i<66) ? src[b][t][i]*1e-3 : 0
__global__ __launch_bounds__(256) void k_src_bf16(const float* __restrict__ src,
                                                  __hip_bfloat16* __restrict__ dst) {
    int row = blockIdx.x * 8 + (threadIdx.x >> 5);   // 12800 rows total
    int i = threadIdx.x & 31;
    const float* s = src + (size_t)row * NF;
    __hip_bfloat16* d = dst + (size_t)row * 72;
#pragma unroll
    for (int jj = 0; jj < 3; ++jj) {
        int c = i + jj * 32;
        if (c < 72) d[c] = f2bf((c < NF) ? s[c] * 1e-3f : 0.f);
    }
}

// ---------------- generic MFMA GEMM ----------------
// A-row r maps to element offset (r/TOUT)*SROW + (r%TOUT)*SCOL + SOFF.
// BT row-major [N][KTOT] bf16. C row-major [M][512].
// EPI: 0 tanh->bf16 ; 1 relu->f32 ; 2 relu->bf16
template<int TOUT, size_t SROW, int SCOL, int SOFF, int KTOT, int EPI>
__global__ __launch_bounds__(256) void k_gemm(const __hip_bfloat16* __restrict__ A,
                                              const __hip_bfloat16* __restrict__ BT,
                                              void* __restrict__ Cv) {
    __shared__ short sA[128 * 64];
    __shared__ short sB[128 * 64];
    const int tid = threadIdx.x;
    const int row0 = blockIdx.x * 128, col0 = blockIdx.y * 128;
    const int lane = tid & 63, wid = tid >> 6;
    const int wr = wid >> 1, wc = wid & 1;

    const __hip_bfloat16* gA[4];
    const __hip_bfloat16* gB[4];
#pragma unroll
    for (int it = 0; it < 4; ++it) {
        int c = it * 256 + tid;
        int r = c >> 3, c16 = c & 7;
        int s16 = c16 ^ (r & 7);
        int grow = row0 + r;
        gA[it] = A + (size_t)(grow / TOUT) * SROW + (size_t)(grow % TOUT) * SCOL
                   + SOFF + s16 * 8;
        gB[it] = BT + (size_t)(col0 + r) * KTOT + s16 * 8;
    }

    f32x4 acc[4][4] = {};
    for (int k0 = 0; k0 < KTOT; k0 += 64) {
#pragma unroll
        for (int it = 0; it < 4; ++it) {
            int c = it * 256 + tid;
            gl_lds16(gA[it] + k0, sA + c * 8);
            gl_lds16(gB[it] + k0, sB + c * 8);
        }
        __syncthreads();
#pragma unroll
        for (int kk = 0; kk < 2; ++kk) {
            bf16x8 af[4], bfr[4];
#pragma unroll
            for (int m = 0; m < 4; ++m) {
                int row = wr * 64 + m * 16 + (lane & 15);
                int c16 = (kk * 4 + (lane >> 4)) ^ (row & 7);
                af[m] = *(const bf16x8*)&sA[row * 64 + c16 * 8];
            }
#pragma unroll
            for (int n = 0; n < 4; ++n) {
                int row = wc * 64 + n * 16 + (lane & 15);
                int c16 = (kk * 4 + (lane >> 4)) ^ (row & 7);
                bfr[n] = *(const bf16x8*)&sB[row * 64 + c16 * 8];
            }
#pragma unroll
            for (int m = 0; m < 4; ++m)
#pragma unroll
                for (int n = 0; n < 4; ++n)
                    acc[m][n] = __builtin_amdgcn_mfma_f32_16x16x32_bf16(
                        af[m], bfr[n], acc[m][n], 0, 0, 0);
        }
        __syncthreads();
    }
#pragma unroll
    for (int m = 0; m < 4; ++m) {
#pragma unroll
        for (int n = 0; n < 4; ++n) {
            int col = col0 + wc * 64 + n * 16 + (lane & 15);
#pragma unroll
            for (int j = 0; j < 4; ++j) {
                int row = row0 + wr * 64 + m * 16 + (lane >> 4) * 4 + j;
                float v = acc[m][n][j];
                if constexpr (EPI == 0) {
                    ((__hip_bfloat16*)Cv)[(size_t)row * DM + col] = f2bf(tanh_fast(v));
                } else if constexpr (EPI == 1) {
                    ((float*)Cv)[(size_t)row * DM + col] = fmaxf(v, 0.f);
                } else {
                    ((__hip_bfloat16*)Cv)[(size_t)row * DM + col] = f2bf(fmaxf(v, 0.f));
                }
            }
        }
    }
}

// ---------------- MFMA amix: hA = bf16(0.9*A@h + 0.1*h0) per batch ----------------
// Block = (b, 256-col d-chunk), 4 waves. A padded [80][96] bf16 (global, L1-hot).
// h^T staged in LDS [d=256][k=104pad] so B-fragments read 8 contiguous k.
// R9 post-mortem: three VALU variants all stuck at ~60us (dep-chain + per-n A-load
// serialization); this moves the 2 GFLOP onto the matrix pipe.
__global__ __launch_bounds__(256) void k_amix_mfma(const __hip_bfloat16* __restrict__ Ab,
                                                   const __hip_bfloat16* __restrict__ h,
                                                   const __hip_bfloat16* __restrict__ h0,
                                                   __hip_bfloat16* __restrict__ m) {
    __shared__ short sHT[256 * 104];   // 53,248 B; [d][k] stride 104
    const int b = blockIdx.x, d0 = blockIdx.y * 256, tid = threadIdx.x;
    const int lane = tid & 63, wid = tid >> 6;

    // stage h[b][k][d0+tid] -> sHT[tid][k], zero-pad k=66..95 (pairs -> b32 writes)
    const unsigned short* hb = (const unsigned short*)(h + (size_t)b * NF * DM + d0);
#pragma unroll
    for (int k = 0; k < 96; k += 2) {
        unsigned int v0 = (k < NF)     ? hb[(size_t)k * DM + tid]       : 0u;
        unsigned int v1 = (k + 1 < NF) ? hb[(size_t)(k + 1) * DM + tid] : 0u;
        *(unsigned int*)&sHT[tid * 104 + k] = v0 | (v1 << 16);
    }
    __syncthreads();

    f32x4 acc[5][4] = {};                  // [mtile][ntile]
    const int nbase = wid * 64;            // wave's 64-col slice
#pragma unroll
    for (int ks = 0; ks < 3; ++ks) {
        int c16 = ks * 4 + (lane >> 4);
        bf16x8 af[5];
#pragma unroll
        for (int mt = 0; mt < 5; ++mt) {
            int row = mt * 16 + (lane & 15);
            af[mt] = *(const bf16x8*)(Ab + (size_t)row * 96 + c16 * 8);
        }
#pragma unroll
        for (int nt = 0; nt < 4; ++nt) {
            int n = nbase + nt * 16 + (lane & 15);
            bf16x8 bfr = *(const bf16x8*)&sHT[n * 104 + c16 * 8];
#pragma unroll
            for (int mt = 0; mt < 5; ++mt)
                acc[mt][nt] = __builtin_amdgcn_mfma_f32_16x16x32_bf16(
                    af[mt], bfr, acc[mt][nt], 0, 0, 0);
        }
    }

    // epilogue: col = lane&15 (d), row f = mt*16 + (lane>>4)*4 + j ; store f<66
    const __hip_bfloat16* h0b = h0 + (size_t)b * NF * DM;
    __hip_bfloat16* mb = m + (size_t)b * NF * DM;
#pragma unroll
    for (int mt = 0; mt < 5; ++mt) {
#pragma unroll
        for (int nt = 0; nt < 4; ++nt) {
            int col = d0 + nbase + nt * 16 + (lane & 15);
#pragma unroll
            for (int j = 0; j < 4; ++j) {
                int f = mt * 16 + (lane >> 4) * 4 + j;
                if (f < NF) {
                    size_t o = (size_t)f * DM + col;
                    mb[o] = f2bf(0.9f * acc[mt][nt][j]
                                 + 0.1f * __bfloat162float(h0b[o]));
                }
            }
        }
    }
}

// ---------------- Wout MFMA: dct_in += h @ WoutT (N=16, 10 valid) ----------------
__global__ __launch_bounds__(256) void k_wout(const __hip_bfloat16* __restrict__ h,
                                              const __hip_bfloat16* __restrict__ woT,
                                              float* __restrict__ dct_in) {
    __shared__ short sA[128 * 64];
    __shared__ short sB[16 * 512];
    const int tid = threadIdx.x;
    const int row0 = blockIdx.x * 128;
    const int lane = tid & 63, wid = tid >> 6;

#pragma unroll
    for (int it = 0; it < 4; ++it) {
        int c = it * 256 + tid;
        int n = c >> 6, c16 = c & 63;
        int s16 = (c16 & 56) | ((c16 & 7) ^ (n & 7));
        gl_lds16(woT + (size_t)n * DM + s16 * 8, sB + c * 8);
    }
    const __hip_bfloat16* gA[4];
#pragma unroll
    for (int it = 0; it < 4; ++it) {
        int c = it * 256 + tid;
        int r = c >> 3, c16 = c & 7;
        gA[it] = h + (size_t)(row0 + r) * DM + (c16 ^ (r & 7)) * 8;
    }

    f32x4 acc[2] = {};
    for (int k0 = 0; k0 < DM; k0 += 64) {
#pragma unroll
        for (int it = 0; it < 4; ++it) {
            int c = it * 256 + tid;
            gl_lds16(gA[it] + k0, sA + c * 8);
        }
        __syncthreads();
#pragma unroll
        for (int kk = 0; kk < 2; ++kk) {
            bf16x8 bfr;
            {
                int n = lane & 15;
                int kb = (k0 >> 3) + kk * 4 + (lane >> 4);
                int slot = (kb & 56) | ((kb & 7) ^ (n & 7));
                bfr = *(const bf16x8*)&sB[n * DM + slot * 8];
            }
#pragma unroll
            for (int mm = 0; mm < 2; ++mm) {
                int row = wid * 32 + mm * 16 + (lane & 15);
                int c16 = (kk * 4 + (lane >> 4)) ^ (row & 7);
                bf16x8 af = *(const bf16x8*)&sA[row * 64 + c16 * 8];
                acc[mm] = __builtin_amdgcn_mfma_f32_16x16x32_bf16(af, bfr, acc[mm], 0, 0, 0);
            }
        }
        __syncthreads();
    }
    int col = lane & 15;
    if (col < DCTN) {
#pragma unroll
        for (int mm = 0; mm < 2; ++mm) {
#pragma unroll
            for (int j = 0; j < 4; ++j) {
                int row = row0 + wid * 32 + mm * 16 + (lane >> 4) * 4 + j;
                size_t o = (size_t)row * DCTN + col;
                dct_in[o] += acc[mm][j];
            }
        }
    }
}

// idct per batch: out[b][l][f] = sum_d dct[d*20+l] * dct_in[b][f][d]
__global__ __launch_bounds__(256) void k_idct(const float* __restrict__ dct_in,
                                              const float* __restrict__ dct,
                                              float* __restrict__ outj) {
    int b = blockIdx.x;
    __shared__ float s_do[NF * DCTN];
    __shared__ float s_dct[400];
    for (int i = threadIdx.x; i < NF * DCTN; i += 256)
        s_do[i] = dct_in[(size_t)b * NF * DCTN + i];
    for (int i = threadIdx.x; i < 400; i += 256) s_dct[i] = dct[i];
    __syncthreads();
    for (int i = threadIdx.x; i < VL * NF; i += 256) {
        int l = i / NF, f = i % NF;
        float a = 0.f;
#pragma unroll
        for (int d = 0; d < DCTN; ++d) a += s_dct[d * VL + l] * s_do[f * DCTN + d];
        outj[((size_t)b * VL + l) * NF + f] = a;
    }
}

// ---------------- attention ----------------
__global__ __launch_bounds__(512) void k_att(const float* __restrict__ qt,
                                             const float* __restrict__ keyt,
                                             float* __restrict__ att) {
    int b = blockIdx.x;
    __shared__ float s_sc[NWIN];
    int wave = threadIdx.x >> 6, lane = threadIdx.x & 63;
    const float* qp = qt + (size_t)b * DM;
    for (int k = wave; k < NWIN; k += 8) {
        const float* kp = keyt + ((size_t)b * NWIN + k) * DM;
        float p = 0.f;
        for (int d = lane; d < DM; d += 64) p += qp[d] * kp[d];
#pragma unroll
        for (int off = 32; off; off >>= 1) p += __shfl_down(p, off);
        if (lane == 0) s_sc[k] = p + 1e-15f;
    }
    __syncthreads();
    if (threadIdx.x == 0) {
        float s = 0.f;
        for (int k = 0; k < NWIN; ++k) s += s_sc[k];
        float inv = 1.f / s;
        for (int k = 0; k < NWIN; ++k) att[(size_t)b * 32 + k] = s_sc[k] * inv;
    }
}

__global__ __launch_bounds__(256) void k_dctatt(const float* __restrict__ src,
                                                const float* __restrict__ att,
                                                const float* __restrict__ dct,
                                                float* __restrict__ dct_att,
                                                float* __restrict__ dct_in) {
    int b = blockIdx.x;
    __shared__ float s_src[50 * NF];
    __shared__ float s_att[NWIN];
    __shared__ float s_ws[VL * NF];
    const float* sb = src + (size_t)b * 50 * NF;
    for (int i = threadIdx.x; i < 50 * NF; i += 256) s_src[i] = sb[i];
    if (threadIdx.x < NWIN) s_att[threadIdx.x] = att[(size_t)b * 32 + threadIdx.x];
    __syncthreads();
    for (int i = threadIdx.x; i < VL * NF; i += 256) {
        int l = i / NF, f = i % NF;
        float a = 0.f;
        for (int v = 0; v < NWIN; ++v) a += s_att[v] * s_src[(v + l) * NF + f];
        s_ws[i] = a;
    }
    __syncthreads();
    for (int i = threadIdx.x; i < NF * DCTN; i += 256) {
        int f = i / DCTN, d = i % DCTN;
        float a = 0.f, c = 0.f;
#pragma unroll
        for (int l = 0; l < VL; ++l) {
            float dm = dct[d * VL + l];
            a += dm * s_ws[l * NF + f];
            int t2 = (l < 10) ? (40 + l) : 49;
            c += dm * s_src[t2 * NF + f];
        }
        dct_att[(size_t)b * NF * DCTN + i] = a;
        dct_in[(size_t)b * NF * DCTN + i] = c;
    }
}

// ---------------- GCN small kernels ----------------
// f-split 2-way for occupancy (grid.y = 2, 33 f-rows per block)
__global__ __launch_bounds__(512) void k_h0(const float* __restrict__ dct_in,
                                            const float* __restrict__ dct_att,
                                            const float* __restrict__ Win,
                                            const __hip_bfloat16* __restrict__ his,
                                            __hip_bfloat16* __restrict__ h0) {
    int b = blockIdx.x, d = threadIdx.x;
    int f0 = blockIdx.y * 33;
    __shared__ float s_x[33 * VL];
    for (int i = threadIdx.x; i < 33 * DCTN; i += 512) {
        int f = i / DCTN, c = i % DCTN;
        size_t gi = (size_t)b * NF * DCTN + (size_t)(f0 + f) * DCTN + c;
        s_x[f * VL + c]      = dct_in[gi];
        s_x[f * VL + 10 + c] = dct_att[gi];
    }
    __syncthreads();
    float w[VL];
#pragma unroll
    for (int c = 0; c < VL; ++c) w[c] = Win[c * DM + d];
    const __hip_bfloat16* hisb = his + (size_t)b * NF * DM + (size_t)f0 * DM + d;
    __hip_bfloat16* h0b = h0 + (size_t)b * NF * DM + (size_t)f0 * DM + d;
    for (int f = 0; f < 33; ++f) {
        float a = 0.f;
#pragma unroll
        for (int c = 0; c < VL; ++c) a += s_x[f * VL + c] * w[c];
        float v = tanh_fast(a);
        if (his) v += __bfloat162float(hisb[(size_t)f * DM]);
        h0b[(size_t)f * DM] = f2bf(v);
    }
}

extern "C" void kernel_launch(void* const* d_in, const int* in_sizes, int n_in,
                              void* d_out, int out_size, void* d_ws, size_t ws_size,
                              hipStream_t stream) {
    const float* src  = (const float*)d_in[0];
    const float* wQ1  = (const float*)d_in[1];
    const float* wQ2  = (const float*)d_in[2];
    const float* wK1  = (const float*)d_in[3];
    const float* wK2  = (const float*)d_in[4];
    const float* Win  = (const float*)d_in[5];
    const float* Agcn = (const float*)d_in[6];
    const float* Wl   = (const float*)d_in[7];
    const float* Wout = (const float*)d_in[8];
    char* ws = (char*)d_ws;
    float* out = (float*)d_out;

    float* dct      = (float*)(ws + B_DCT);
    float* keyt     = (float*)(ws + B_KEYT);
    float* qt       = (float*)(ws + B_QT);
    float* dct_att  = (float*)(ws + B_DA);
    float* dct_in   = (float*)(ws + B_DI);
    float* att      = (float*)(ws + B_ATT);
    __hip_bfloat16* h0b = (__hip_bfloat16*)(ws + B_H0);
    __hip_bfloat16* WpT = (__hip_bfloat16*)(ws + B_WPT);
    __hip_bfloat16* wTK = (__hip_bfloat16*)(ws + B_WTK);
    __hip_bfloat16* wTQ = (__hip_bfloat16*)(ws + B_WTQ);
    __hip_bfloat16* w1K = (__hip_bfloat16*)(ws + B_W1K);
    __hip_bfloat16* w1Q = (__hip_bfloat16*)(ws + B_W1Q);
    __hip_bfloat16* woT = (__hip_bfloat16*)(ws + B_WOT);
    __hip_bfloat16* srcb= (__hip_bfloat16*)(ws + B_SRCB);
    __hip_bfloat16* t1K = (__hip_bfloat16*)(ws + B_T1K);
    __hip_bfloat16* t1Q = (__hip_bfloat16*)(ws + B_T1Q);
    __hip_bfloat16* hA  = (__hip_bfloat16*)(ws + B_HA);
    __hip_bfloat16* hB  = (__hip_bfloat16*)(ws + B_HB);
    __hip_bfloat16* Ab  = (__hip_bfloat16*)(ws + B_AB);

    k_build_dct<<<1, 512, 0, stream>>>(dct);
    k_build_wpT<<<dim3(16, 16, 18), 256, 0, stream>>>(Wl, WpT);
    k_build_wcT<<<512, 256, 0, stream>>>(wK2, wTK);
    k_build_wcT<<<512, 256, 0, stream>>>(wQ2, wTQ);
    k_build_w1T<<<512, 256, 0, stream>>>(wK1, w1K);
    k_build_w1T<<<512, 256, 0, stream>>>(wQ1, w1Q);
    k_build_woutT<<<3, 256, 0, stream>>>(Wout, woT);
    k_build_ab<<<3, 256, 0, stream>>>(Agcn, Ab);
    k_src_bf16<<<1600, 256, 0, stream>>>(src, srcb);

    // conv stacks as implicit GEMMs
    k_gemm<35, 3600, 72, 0,    448, 2><<<dim3(70, 4), 256, 0, stream>>>(srcb, w1K, t1K);
    k_gemm<31, 17920, 512, 0, 2560, 1><<<dim3(62, 4), 256, 0, stream>>>(t1K, wTK, keyt);
    k_gemm<5, 3600, 72, 2880,  448, 2><<<dim3(10, 4), 256, 0, stream>>>(srcb, w1Q, t1Q);
    k_gemm<1, 2560, 0, 0,     2560, 1><<<dim3(2, 4), 256, 0, stream>>>(t1Q, wTQ, qt);

    k_att<<<BSZ, 512, 0, stream>>>(qt, keyt, att);
    k_dctatt<<<BSZ, 256, 0, stream>>>(src, att, dct, dct_att, dct_in);

    for (int j = 0; j < 3; ++j) {
        k_h0<<<dim3(BSZ, 2), 512, 0, stream>>>(dct_in, dct_att,
                                               Win + (size_t)j * VL * DM,
                                               j == 0 ? nullptr : hB, h0b);
        for (int l = 0; l < 6; ++l) {
            k_amix_mfma<<<dim3(BSZ, 2), 256, 0, stream>>>(
                Ab + (size_t)j * 80 * 96, l == 0 ? h0b : hB, h0b, hA);
            k_gemm<1, 512, 0, 0, 512, 0><<<dim3(132, 4), 256, 0, stream>>>(
                hA, WpT + (size_t)(j * 6 + l) * DM * DM, hB);
        }
        k_wout<<<132, 256, 0, stream>>>(hB, woT + (size_t)j * 16 * DM, dct_in);
        k_idct<<<BSZ, 256, 0, stream>>>(dct_in, dct, out + (size_t)j * BSZ * VL * NF);
    }
}